// Round 7
// baseline (295.053 us; speedup 1.0000x reference)
//
#include <hip/hip_runtime.h>
#include <hip/hip_bf16.h>

#define B_ 4
#define S_ 1024
#define D_ 256
#define H_ 8
#define LRELU_ALPHA 0.2f
#define MAXDEG 128

typedef __attribute__((ext_vector_type(8))) short short8;
typedef __attribute__((ext_vector_type(4))) float floatx4;

__device__ __forceinline__ float bf2f(unsigned short u) {
    union { unsigned int i; float f; } c; c.i = ((unsigned int)u) << 16; return c.f;
}
__device__ __forceinline__ unsigned short f2bf(float f) {
    union { float f; unsigned int u; } c; c.f = f;
    unsigned int r = (c.u + 0x7FFF + ((c.u >> 16) & 1)) >> 16;
    return (unsigned short)r;
}

// ---------------- CSR build ----------------
__global__ __launch_bounds__(1024) void k_csr(const float* __restrict__ adj,
        int* __restrict__ nbr, int* __restrict__ cnt) {
    int row = blockIdx.x;
    int j = threadIdx.x;
    __shared__ int c;
    if (j == 0) c = 0;
    __syncthreads();
    float a = adj[(size_t)row * S_ + j];
    if (a > 0.f) {
        int s = atomicAdd(&c, 1);
        if (s < MAXDEG) nbr[row * MAXDEG + s] = j;
    }
    __syncthreads();
    if (j == 0) cnt[row] = c < MAXDEG ? c : MAXDEG;
}

// ---------------- fp32 -> bf16 ----------------
__global__ void k_cast4(const float* __restrict__ x, unsigned short* __restrict__ o, int n4) {
    int i = blockIdx.x * blockDim.x + threadIdx.x;
    if (i >= n4) return;
    float4 v = ((const float4*)x)[i];
    ushort4 u; u.x = f2bf(v.x); u.y = f2bf(v.y); u.z = f2bf(v.z); u.w = f2bf(v.w);
    ((ushort4*)o)[i] = u;
}

// ---------------- W[K][N] fp32 -> Bt[N][K] bf16 ----------------
__global__ __launch_bounds__(256) void k_castT(const float* __restrict__ W,
        unsigned short* __restrict__ out, int K, int N) {
    __shared__ float t[32][33];
    int k0 = blockIdx.x * 32, n0 = blockIdx.y * 32;
    int tx = threadIdx.x & 31, ty = threadIdx.x >> 5;
#pragma unroll
    for (int i = 0; i < 4; ++i)
        t[ty + 8 * i][tx] = W[(size_t)(k0 + ty + 8 * i) * N + n0 + tx];
    __syncthreads();
#pragma unroll
    for (int i = 0; i < 4; ++i)
        out[(size_t)(n0 + ty + 8 * i) * K + k0 + tx] = f2bf(t[tx][ty + 8 * i]);
}

// --- W2[256 k][2048 (h*256+d)] -> Bt2[256 d][2048 (h*256+k)] bf16 ---
__global__ __launch_bounds__(256) void k_castT2(const float* __restrict__ W2,
        unsigned short* __restrict__ out) {
    __shared__ float t[32][33];
    int k0 = blockIdx.x * 32, d0 = blockIdx.y * 32, h = blockIdx.z;
    int tx = threadIdx.x & 31, ty = threadIdx.x >> 5;
#pragma unroll
    for (int i = 0; i < 4; ++i)
        t[ty + 8 * i][tx] = W2[(size_t)(k0 + ty + 8 * i) * 2048 + h * 256 + d0 + tx];
    __syncthreads();
#pragma unroll
    for (int i = 0; i < 4; ++i)
        out[(size_t)(d0 + ty + 8 * i) * 2048 + h * 256 + k0 + tx] = f2bf(t[tx][ty + 8 * i]);
}

// --- w_s2[h][k] = sum_d W2[k][h*256+d]*as2[h][d]; likewise w_d2 ---
__global__ __launch_bounds__(256) void k_wvec2(const float* __restrict__ W2,
        const float* __restrict__ as2, const float* __restrict__ ad2,
        float* __restrict__ WS2, float* __restrict__ WD2) {
    int h = blockIdx.x, k = threadIdx.x;
    const float* wrow = W2 + (size_t)k * 2048 + h * 256;
    float s = 0.f, d = 0.f;
    for (int dd = 0; dd < 256; ++dd) {
        float w = wrow[dd];
        s += w * as2[h * 256 + dd];
        d += w * ad2[h * 256 + dd];
    }
    WS2[h * 256 + k] = s;
    WD2[h * 256 + k] = d;
}

// ------- split-K MFMA GEMM: P[z][M][N] += A[M,kslice]bf16 @ Bt[N,kslice]bf16 -------
// grid (N/64, M/64, nsplit); Kc = K/nsplit. Register-prefetch double buffer.
__global__ __launch_bounds__(256) void k_gemm_mfma(const unsigned short* __restrict__ A,
        const unsigned short* __restrict__ Bt, float* __restrict__ P,
        int M, int N, int K, int Kc) {
    __shared__ unsigned short As[64][40];
    __shared__ unsigned short Bs[64][40];
    int tid = threadIdx.x;
    int bm = blockIdx.y * 64, bn = blockIdx.x * 64;
    int kbeg = blockIdx.z * Kc, kend = kbeg + Kc;
    int lane = tid & 63, wv = tid >> 6;
    int wm = (wv & 1) * 32, wn = (wv >> 1) * 32;
    int lrow = lane & 15, lq = lane >> 4;
    floatx4 acc00 = {0.f,0.f,0.f,0.f}, acc01 = acc00, acc10 = acc00, acc11 = acc00;
    int sm = tid >> 2, skq = (tid & 3) * 8;
    const unsigned short* Ap = A + (size_t)(bm + sm) * K + skq;
    const unsigned short* Bp = Bt + (size_t)(bn + sm) * K + skq;
    short8 av = *(const short8*)(Ap + kbeg);
    short8 bv = *(const short8*)(Bp + kbeg);
    for (int k0 = kbeg; k0 < kend; k0 += 32) {
        *(short8*)&As[sm][skq] = av;
        *(short8*)&Bs[sm][skq] = bv;
        __syncthreads();
        if (k0 + 32 < kend) {            // prefetch next tile during MFMA
            av = *(const short8*)(Ap + k0 + 32);
            bv = *(const short8*)(Bp + k0 + 32);
        }
        short8 a0 = *(const short8*)&As[wm + lrow][lq * 8];
        short8 a1 = *(const short8*)&As[wm + 16 + lrow][lq * 8];
        short8 b0 = *(const short8*)&Bs[wn + lrow][lq * 8];
        short8 b1 = *(const short8*)&Bs[wn + 16 + lrow][lq * 8];
        acc00 = __builtin_amdgcn_mfma_f32_16x16x32_bf16(a0, b0, acc00, 0, 0, 0);
        acc01 = __builtin_amdgcn_mfma_f32_16x16x32_bf16(a0, b1, acc01, 0, 0, 0);
        acc10 = __builtin_amdgcn_mfma_f32_16x16x32_bf16(a1, b0, acc10, 0, 0, 0);
        acc11 = __builtin_amdgcn_mfma_f32_16x16x32_bf16(a1, b1, acc11, 0, 0, 0);
        __syncthreads();
    }
    float* out = P + (size_t)blockIdx.z * M * N;
#pragma unroll
    for (int mi = 0; mi < 2; ++mi)
#pragma unroll
        for (int ni = 0; ni < 2; ++ni) {
            floatx4 a = mi == 0 ? (ni == 0 ? acc00 : acc01) : (ni == 0 ? acc10 : acc11);
#pragma unroll
            for (int r = 0; r < 4; ++r) {
                int grow = bm + wm + mi * 16 + lq * 4 + r;
                int gcol = bn + wn + ni * 16 + lrow;
                out[(size_t)grow * N + gcol] = a[r];
            }
        }
}

// ---------------- split reduce -> bf16 ----------------
__global__ void k_red_bf16(const float* __restrict__ P, unsigned short* __restrict__ out,
                           int n, int nsplit) {
    int i = blockIdx.x * blockDim.x + threadIdx.x;
    if (i >= (n >> 2)) return;
    float4 s = ((const float4*)P)[i];
    for (int sp = 1; sp < nsplit; ++sp) {
        float4 v = ((const float4*)(P + (size_t)sp * n))[i];
        s.x += v.x; s.y += v.y; s.z += v.z; s.w += v.w;
    }
    ushort4 u; u.x = f2bf(s.x); u.y = f2bf(s.y); u.z = f2bf(s.z); u.w = f2bf(s.w);
    ((ushort4*)out)[i] = u;
}

// ---------------- split reduce + bias + gelu -> bf16 ----------------
__global__ void k_red_gelu(const float* __restrict__ P, const float* __restrict__ b1,
                           unsigned short* __restrict__ out, int n, int nsplit, int cmask4) {
    int i = blockIdx.x * blockDim.x + threadIdx.x;
    if (i >= (n >> 2)) return;
    float4 s = ((const float4*)P)[i];
    for (int sp = 1; sp < nsplit; ++sp) {
        float4 v = ((const float4*)(P + (size_t)sp * n))[i];
        s.x += v.x; s.y += v.y; s.z += v.z; s.w += v.w;
    }
    float4 bb = ((const float4*)b1)[i & cmask4];
    float xs[4] = {s.x + bb.x, s.y + bb.y, s.z + bb.z, s.w + bb.w};
    ushort4 u;
    unsigned short* up = (unsigned short*)&u;
#pragma unroll
    for (int q = 0; q < 4; ++q) {
        float x = xs[q];
        float t = tanhf(0.7978845608028654f * (x + 0.044715f * x * x * x));
        up[q] = f2bf(0.5f * x * (1.f + t));
    }
    ((ushort4*)out)[i] = u;
}

// ---------------- split reduce + residual + bias -> fp32 (final) ----------------
__global__ void k_red_final(const float* __restrict__ P, const float* __restrict__ HLN,
                            const float* __restrict__ b2, float* __restrict__ out,
                            int n, int nsplit) {
    int i = blockIdx.x * blockDim.x + threadIdx.x;
    if (i >= (n >> 2)) return;
    float4 s = ((const float4*)HLN)[i];
    float4 bb = ((const float4*)b2)[i & 63];
    s.x += bb.x; s.y += bb.y; s.z += bb.z; s.w += bb.w;
    for (int sp = 0; sp < nsplit; ++sp) {
        float4 v = ((const float4*)(P + (size_t)sp * n))[i];
        s.x += v.x; s.y += v.y; s.z += v.z; s.w += v.w;
    }
    ((float4*)out)[i] = s;
}

// ---------------- scores from bf16 hp (layers 0/1, dh=32) ----------------
__global__ __launch_bounds__(256) void k_scores(const unsigned short* __restrict__ hp,
        const float* __restrict__ asrc, const float* __restrict__ adst,
        float* __restrict__ src, float* __restrict__ dst, int dh) {
    int w = blockIdx.x * 4 + (threadIdx.x >> 6);
    int lane = threadIdx.x & 63;
    int h = w & (H_ - 1);
    int bs = w >> 3;
    const unsigned short* v = hp + (size_t)bs * H_ * dh + (size_t)h * dh;
    float s = 0.f, d = 0.f;
    for (int k = lane; k < dh; k += 64) {
        float x = bf2f(v[k]);
        s += x * asrc[h * dh + k];
        d += x * adst[h * dh + k];
    }
    for (int o = 32; o; o >>= 1) { s += __shfl_xor(s, o); d += __shfl_xor(d, o); }
    if (lane == 0) { src[w] = s; dst[w] = d; }
}

// ---------------- layer-2 scores straight from fp32 H via WS2/WD2 ----------------
__global__ __launch_bounds__(256) void k_scores2H(const float* __restrict__ H,
        const float* __restrict__ WS2, const float* __restrict__ WD2,
        float* __restrict__ src, float* __restrict__ dst) {
    int row = blockIdx.x * 4 + (threadIdx.x >> 6);
    int lane = threadIdx.x & 63;
    float4 v = ((const float4*)(H + (size_t)row * 256))[lane];
#pragma unroll
    for (int h = 0; h < 8; ++h) {
        float4 ws = ((const float4*)(WS2 + h * 256))[lane];
        float4 wd = ((const float4*)(WD2 + h * 256))[lane];
        float s = v.x * ws.x + v.y * ws.y + v.z * ws.z + v.w * ws.w;
        float d = v.x * wd.x + v.y * wd.y + v.z * wd.z + v.w * wd.w;
        for (int o = 32; o; o >>= 1) { s += __shfl_xor(s, o); d += __shfl_xor(d, o); }
        if (lane == 0) { src[row * 8 + h] = s; dst[row * 8 + h] = d; }
    }
}

// ------- attn layers 0/1 fused: out = elu(agg + X), fp32 + bf16 copies -------
__global__ __launch_bounds__(256) void k_attn_small_f(const unsigned short* __restrict__ hp,
        const float* __restrict__ src, const float* __restrict__ dst,
        const int* __restrict__ nbr, const int* __restrict__ cnts,
        const float* __restrict__ X, float* __restrict__ Hout,
        unsigned short* __restrict__ Hb) {
    int row = blockIdx.x;
    int tid = threadIdx.x;
    int rb = row & ~(S_ - 1);
    __shared__ int nb[MAXDEG];
    __shared__ float ss[8];
    __shared__ float ew[MAXDEG * 9];
    int cnt = cnts[row];
    for (int t = tid; t < cnt; t += 256) nb[t] = nbr[row * MAXDEG + t];
    if (tid < 8) ss[tid] = src[row * H_ + tid];
    __syncthreads();
    for (int idx = tid; idx < cnt * 8; idx += 256) {
        int n = idx >> 3, h = idx & 7;
        int j = nb[n];
        float e = ss[h] + dst[(rb + j) * H_ + h];
        ew[n * 9 + h] = e > 0.f ? e : LRELU_ALPHA * e;
    }
    __syncthreads();
    {
        int lane = tid & 63, wv = tid >> 6;
        int h = wv * 2 + (lane >> 5), sub = lane & 31;
        float m = -1e30f;
        for (int n = sub; n < cnt; n += 32) m = fmaxf(m, ew[n * 9 + h]);
        for (int o = 16; o; o >>= 1) m = fmaxf(m, __shfl_xor(m, o));
        float s = 0.f;
        for (int n = sub; n < cnt; n += 32) {
            float v = __expf(ew[n * 9 + h] - m); ew[n * 9 + h] = v; s += v;
        }
        for (int o = 16; o; o >>= 1) s += __shfl_xor(s, o);
        float inv = s > 0.f ? 1.f / s : 0.f;
        for (int n = sub; n < cnt; n += 32) ew[n * 9 + h] *= inv;
    }
    __syncthreads();
    int h = tid >> 5;
    float acc0 = 0.f, acc1 = 0.f;
    const unsigned short* hpb = hp + (size_t)rb * 256;
    int n = 0;
    for (; n + 1 < cnt; n += 2) {
        int j0 = nb[n], j1 = nb[n + 1];
        float w0 = ew[n * 9 + h], w1 = ew[(n + 1) * 9 + h];
        acc0 += w0 * bf2f(hpb[(size_t)j0 * 256 + tid]);
        acc1 += w1 * bf2f(hpb[(size_t)j1 * 256 + tid]);
    }
    if (n < cnt) acc0 += ew[n * 9 + h] * bf2f(hpb[(size_t)nb[n] * 256 + tid]);
    float o = acc0 + acc1 + X[(size_t)row * 256 + tid];
    o = o > 0.f ? o : (__expf(o) - 1.f);
    Hout[(size_t)row * 256 + tid] = o;
    Hb[(size_t)row * 256 + tid] = f2bf(o);
}

// ------- layer-2 aggregation over H rows: Ycat[row][h*256+k] = (attn_h/8 @ H)[k] -------
__global__ __launch_bounds__(256) void k_attn_Y(const unsigned short* __restrict__ Hb,
        const float* __restrict__ src2, const float* __restrict__ dst2,
        const int* __restrict__ nbr, const int* __restrict__ cnts,
        unsigned short* __restrict__ Ycat) {
    int row = blockIdx.x;
    int tid = threadIdx.x;
    int rb = row & ~(S_ - 1);
    __shared__ int nb[MAXDEG];
    __shared__ float ss[8];
    __shared__ float ew[MAXDEG * 10];
    int cnt = cnts[row];
    for (int t = tid; t < cnt; t += 256) nb[t] = nbr[row * MAXDEG + t];
    if (tid < 8) ss[tid] = src2[row * H_ + tid];
    __syncthreads();
    for (int idx = tid; idx < cnt * 8; idx += 256) {
        int n = idx >> 3, h = idx & 7;
        int j = nb[n];
        float e = ss[h] + dst2[(rb + j) * H_ + h];
        ew[n * 10 + h] = e > 0.f ? e : LRELU_ALPHA * e;
    }
    __syncthreads();
    {
        int lane = tid & 63, wv = tid >> 6;
        int h = wv * 2 + (lane >> 5), sub = lane & 31;
        float m = -1e30f;
        for (int n = sub; n < cnt; n += 32) m = fmaxf(m, ew[n * 10 + h]);
        for (int o = 16; o; o >>= 1) m = fmaxf(m, __shfl_xor(m, o));
        float s = 0.f;
        for (int n = sub; n < cnt; n += 32) {
            float v = __expf(ew[n * 10 + h] - m); ew[n * 10 + h] = v; s += v;
        }
        for (int o = 16; o; o >>= 1) s += __shfl_xor(s, o);
        float inv = s > 0.f ? 0.125f / s : 0.f;
        for (int n = sub; n < cnt; n += 32) ew[n * 10 + h] *= inv;
    }
    __syncthreads();
    float acc[8] = {0.f,0.f,0.f,0.f,0.f,0.f,0.f,0.f};
    for (int n = 0; n < cnt; ++n) {
        int j = nb[n];
        float v = bf2f(Hb[(size_t)(rb + j) * 256 + tid]);
        const float2* w = (const float2*)&ew[n * 10];
        float2 w01 = w[0], w23 = w[1], w45 = w[2], w67 = w[3];
        acc[0] += w01.x * v; acc[1] += w01.y * v;
        acc[2] += w23.x * v; acc[3] += w23.y * v;
        acc[4] += w45.x * v; acc[5] += w45.y * v;
        acc[6] += w67.x * v; acc[7] += w67.y * v;
    }
#pragma unroll
    for (int h = 0; h < 8; ++h)
        Ycat[(size_t)row * 2048 + h * 256 + tid] = f2bf(acc[h]);
}

// ------- 8-way split reduce + residual + LayerNorm, fp32 + bf16 out -------
__global__ __launch_bounds__(256) void k_ln_red(const float* __restrict__ P, int nsplit,
        const float* __restrict__ Hres, const float* __restrict__ g,
        const float* __restrict__ bta, float* __restrict__ HLN,
        unsigned short* __restrict__ HLNb) {
    int row = blockIdx.x * 4 + (threadIdx.x >> 6);
    int lane = threadIdx.x & 63;
    float4 v = ((const float4*)(Hres + (size_t)row * 256))[lane];
    for (int sp = 0; sp < nsplit; ++sp) {
        float4 p = ((const float4*)(P + (size_t)sp * 1048576 + (size_t)row * 256))[lane];
        v.x += p.x; v.y += p.y; v.z += p.z; v.w += p.w;
    }
    float s = v.x + v.y + v.z + v.w;
    float q = v.x * v.x + v.y * v.y + v.z * v.z + v.w * v.w;
    for (int o = 32; o; o >>= 1) { s += __shfl_xor(s, o); q += __shfl_xor(q, o); }
    float mu = s * (1.f / 256.f);
    float var = q * (1.f / 256.f) - mu * mu;
    if (var < 0.f) var = 0.f;
    float rs = rsqrtf(var + 1e-5f);
    float4 gg = ((const float4*)g)[lane];
    float4 bb = ((const float4*)bta)[lane];
    float4 o;
    o.x = (v.x - mu) * rs * gg.x + bb.x;
    o.y = (v.y - mu) * rs * gg.y + bb.y;
    o.z = (v.z - mu) * rs * gg.z + bb.z;
    o.w = (v.w - mu) * rs * gg.w + bb.w;
    ((float4*)(HLN + (size_t)row * 256))[lane] = o;
    ushort4 ob; ob.x = f2bf(o.x); ob.y = f2bf(o.y); ob.z = f2bf(o.z); ob.w = f2bf(o.w);
    ((ushort4*)(HLNb + (size_t)row * 256))[lane] = ob;
}

extern "C" void kernel_launch(void* const* d_in, const int* in_sizes, int n_in,
                              void* d_out, int out_size, void* d_ws, size_t ws_size,
                              hipStream_t stream) {
    const float* adj   = (const float*)d_in[0];
    const float* x     = (const float*)d_in[1];
    const float* W0    = (const float*)d_in[2];
    const float* as0   = (const float*)d_in[3];
    const float* ad0   = (const float*)d_in[4];
    const float* W1    = (const float*)d_in[5];
    const float* as1   = (const float*)d_in[6];
    const float* ad1   = (const float*)d_in[7];
    const float* W2    = (const float*)d_in[8];
    const float* as2   = (const float*)d_in[9];
    const float* ad2   = (const float*)d_in[10];
    const float* ln_g  = (const float*)d_in[11];
    const float* ln_b  = (const float*)d_in[12];
    const float* ff_w1 = (const float*)d_in[13];
    const float* ff_b1 = (const float*)d_in[14];
    const float* ff_w2 = (const float*)d_in[15];
    const float* ff_b2 = (const float*)d_in[16];

    float* ws = (float*)d_ws;
    float* H    = ws;                          // [4096,256] f32
    float* HLN  = ws + 1048576;                // [4096,256] f32
    unsigned short* Ycat = (unsigned short*)(ws + 2097152);   // [4096,2048] bf16
    unsigned short* HPb  = (unsigned short*)(ws + 6291456);   // [4096,256] bf16
    unsigned short* xb   = (unsigned short*)(ws + 6815744);
    unsigned short* Hb   = (unsigned short*)(ws + 7340032);
    unsigned short* HLNb = (unsigned short*)(ws + 7864320);
    unsigned short* MIDb = (unsigned short*)(ws + 8388608);   // [4096,512] bf16
    unsigned short* W0t  = (unsigned short*)(ws + 9437184);   // [256,256]
    unsigned short* W1t  = (unsigned short*)(ws + 9469952);
    unsigned short* W2t  = (unsigned short*)(ws + 9502720);   // [256,2048]
    unsigned short* F1t  = (unsigned short*)(ws + 9764864);   // [512,256]
    unsigned short* F2t  = (unsigned short*)(ws + 9830400);   // [256,512]
    float* WS2 = ws + 9895936;                 // [8,256]
    float* WD2 = ws + 9897984;                 // [8,256]
    float* SRC = ws + 9900032;                 // [4096,8]
    float* DST = ws + 9932800;
    int*   NBR = (int*)(ws + 9965568);         // [4096,128]
    int*   CNT = (int*)(ws + 10489856);
    float* PP  = ws + 12582912;                // split-K partials, up to [8][4096][256] f32

    k_csr<<<4096, 1024, 0, stream>>>(adj, NBR, CNT);
    k_cast4<<<1024, 256, 0, stream>>>(x, xb, 262144);
    k_castT<<<dim3(8, 8),  256, 0, stream>>>(W0, W0t, 256, 256);
    k_castT<<<dim3(8, 8),  256, 0, stream>>>(W1, W1t, 256, 256);
    k_castT2<<<dim3(8, 8, 8), 256, 0, stream>>>(W2, W2t);
    k_castT<<<dim3(8, 16), 256, 0, stream>>>(ff_w1, F1t, 256, 512);
    k_castT<<<dim3(16, 8), 256, 0, stream>>>(ff_w2, F2t, 512, 256);
    k_wvec2<<<8, 256, 0, stream>>>(W2, as2, ad2, WS2, WD2);

    // ---- GAT layer 0 ----
    k_gemm_mfma<<<dim3(4, 64, 4), 256, 0, stream>>>(xb, W0t, PP, 4096, 256, 256, 64);
    k_red_bf16<<<1024, 256, 0, stream>>>(PP, HPb, 1048576, 4);
    k_scores<<<8192, 256, 0, stream>>>(HPb, as0, ad0, SRC, DST, 32);
    k_attn_small_f<<<4096, 256, 0, stream>>>(HPb, SRC, DST, NBR, CNT, x, H, Hb);

    // ---- GAT layer 1 ----
    k_gemm_mfma<<<dim3(4, 64, 4), 256, 0, stream>>>(Hb, W1t, PP, 4096, 256, 256, 64);
    k_red_bf16<<<1024, 256, 0, stream>>>(PP, HPb, 1048576, 4);
    k_scores<<<8192, 256, 0, stream>>>(HPb, as1, ad1, SRC, DST, 32);
    k_attn_small_f<<<4096, 256, 0, stream>>>(HPb, SRC, DST, NBR, CNT, H, H, Hb);

    // ---- GAT layer 2: scores from H, aggregate H, GEMM with W2 (split 8), LN fused ----
    k_scores2H<<<1024, 256, 0, stream>>>(H, WS2, WD2, SRC, DST);
    k_attn_Y<<<4096, 256, 0, stream>>>(Hb, SRC, DST, NBR, CNT, Ycat);
    k_gemm_mfma<<<dim3(4, 64, 8), 256, 0, stream>>>(Ycat, W2t, PP, 4096, 256, 2048, 256);
    k_ln_red<<<1024, 256, 0, stream>>>(PP, 8, H, ln_g, ln_b, HLN, HLNb);

    // ---- FFN ----
    k_gemm_mfma<<<dim3(8, 64, 2), 256, 0, stream>>>(HLNb, F1t, PP, 4096, 512, 256, 128);
    k_red_gelu<<<2048, 256, 0, stream>>>(PP, ff_b1, MIDb, 2097152, 2, 127);
    k_gemm_mfma<<<dim3(4, 64, 4), 256, 0, stream>>>(MIDb, F2t, PP, 4096, 256, 512, 128);
    k_red_final<<<1024, 256, 0, stream>>>(PP, HLN, ff_b2, (float*)d_out, 1048576, 4);
}

// Round 8
// 278.263 us; speedup vs baseline: 1.0603x; 1.0603x over previous
//
#include <hip/hip_runtime.h>
#include <hip/hip_bf16.h>

#define B_ 4
#define S_ 1024
#define D_ 256
#define H_ 8
#define LRELU_ALPHA 0.2f
#define MAXDEG 128

typedef __attribute__((ext_vector_type(8))) short short8;
typedef __attribute__((ext_vector_type(4))) float floatx4;

__device__ __forceinline__ float bf2f(unsigned short u) {
    union { unsigned int i; float f; } c; c.i = ((unsigned int)u) << 16; return c.f;
}
__device__ __forceinline__ unsigned short f2bf(float f) {
    union { float f; unsigned int u; } c; c.f = f;
    unsigned int r = (c.u + 0x7FFF + ((c.u >> 16) & 1)) >> 16;
    return (unsigned short)r;
}

// ---------- fused prep: CSR + x-cast + weight transposes + wvec2, one launch ----------
__device__ void castT_body(const float* __restrict__ W, unsigned short* __restrict__ out,
                           int K, int N, int k0, int n0, float (*t)[33], int tid) {
    int tx = tid & 31, ty = tid >> 5;
#pragma unroll
    for (int i = 0; i < 4; ++i)
        t[ty + 8 * i][tx] = W[(size_t)(k0 + ty + 8 * i) * N + n0 + tx];
    __syncthreads();
#pragma unroll
    for (int i = 0; i < 4; ++i)
        out[(size_t)(n0 + ty + 8 * i) * K + k0 + tx] = f2bf(t[tx][ty + 8 * i]);
}

__global__ __launch_bounds__(256) void k_prep(
        const float* __restrict__ x, unsigned short* __restrict__ xb,
        const float* __restrict__ W0, unsigned short* __restrict__ W0t,
        const float* __restrict__ W1, unsigned short* __restrict__ W1t,
        const float* __restrict__ W2, unsigned short* __restrict__ W2t,
        const float* __restrict__ F1, unsigned short* __restrict__ F1t,
        const float* __restrict__ F2, unsigned short* __restrict__ F2t,
        const float* __restrict__ as2, const float* __restrict__ ad2,
        float* __restrict__ WS2, float* __restrict__ WD2,
        const float* __restrict__ adj, int* __restrict__ nbr, int* __restrict__ cnt) {
    __shared__ float t[32][33];
    __shared__ int c;
    int b = blockIdx.x, tid = threadIdx.x;
    if (b < 1024) {                       // x -> bf16
        int i = b * 256 + tid;
        float4 v = ((const float4*)x)[i];
        ushort4 u; u.x = f2bf(v.x); u.y = f2bf(v.y); u.z = f2bf(v.z); u.w = f2bf(v.w);
        ((ushort4*)xb)[i] = u;
    } else if (b < 1088) {                // W0^T
        int i = b - 1024; castT_body(W0, W0t, 256, 256, (i & 7) * 32, (i >> 3) * 32, t, tid);
    } else if (b < 1152) {                // W1^T
        int i = b - 1088; castT_body(W1, W1t, 256, 256, (i & 7) * 32, (i >> 3) * 32, t, tid);
    } else if (b < 1664) {                // W2 per-head transpose
        int i = b - 1152;
        int k0 = (i & 7) * 32, d0 = ((i >> 3) & 7) * 32, h = i >> 6;
        int tx = tid & 31, ty = tid >> 5;
#pragma unroll
        for (int q = 0; q < 4; ++q)
            t[ty + 8 * q][tx] = W2[(size_t)(k0 + ty + 8 * q) * 2048 + h * 256 + d0 + tx];
        __syncthreads();
#pragma unroll
        for (int q = 0; q < 4; ++q)
            W2t[(size_t)(d0 + ty + 8 * q) * 2048 + h * 256 + k0 + tx] = f2bf(t[tx][ty + 8 * q]);
    } else if (b < 1792) {                // ff_w1^T
        int i = b - 1664; castT_body(F1, F1t, 256, 512, (i & 7) * 32, (i >> 3) * 32, t, tid);
    } else if (b < 1920) {                // ff_w2^T
        int i = b - 1792; castT_body(F2, F2t, 512, 256, (i & 15) * 32, (i >> 4) * 32, t, tid);
    } else if (b < 1928) {                // wvec2
        int h = b - 1920, k = tid;
        const float* wrow = W2 + (size_t)k * 2048 + h * 256;
        float s = 0.f, d = 0.f;
        for (int dd = 0; dd < 256; ++dd) {
            float w = wrow[dd];
            s += w * as2[h * 256 + dd];
            d += w * ad2[h * 256 + dd];
        }
        WS2[h * 256 + k] = s;
        WD2[h * 256 + k] = d;
    } else {                              // CSR build, 4 cols/thread
        int row = b - 1928;
        if (tid == 0) c = 0;
        __syncthreads();
        for (int j = tid; j < S_; j += 256) {
            if (adj[(size_t)row * S_ + j] > 0.f) {
                int s = atomicAdd(&c, 1);
                if (s < MAXDEG) nbr[row * MAXDEG + s] = j;
            }
        }
        __syncthreads();
        if (tid == 0) cnt[row] = c < MAXDEG ? c : MAXDEG;
    }
}

// ------- split-K MFMA GEMM: P[z][M][N] = A[M,kslice]bf16 @ Bt[N,kslice]bf16 -------
__global__ __launch_bounds__(256) void k_gemm_mfma(const unsigned short* __restrict__ A,
        const unsigned short* __restrict__ Bt, float* __restrict__ P,
        int M, int N, int K, int Kc) {
    __shared__ unsigned short As[64][40];
    __shared__ unsigned short Bs[64][40];
    int tid = threadIdx.x;
    int bm = blockIdx.y * 64, bn = blockIdx.x * 64;
    int kbeg = blockIdx.z * Kc, kend = kbeg + Kc;
    int lane = tid & 63, wv = tid >> 6;
    int wm = (wv & 1) * 32, wn = (wv >> 1) * 32;
    int lrow = lane & 15, lq = lane >> 4;
    floatx4 acc00 = {0.f,0.f,0.f,0.f}, acc01 = acc00, acc10 = acc00, acc11 = acc00;
    int sm = tid >> 2, skq = (tid & 3) * 8;
    const unsigned short* Ap = A + (size_t)(bm + sm) * K + skq;
    const unsigned short* Bp = Bt + (size_t)(bn + sm) * K + skq;
    short8 av = *(const short8*)(Ap + kbeg);
    short8 bv = *(const short8*)(Bp + kbeg);
    for (int k0 = kbeg; k0 < kend; k0 += 32) {
        *(short8*)&As[sm][skq] = av;
        *(short8*)&Bs[sm][skq] = bv;
        __syncthreads();
        if (k0 + 32 < kend) {
            av = *(const short8*)(Ap + k0 + 32);
            bv = *(const short8*)(Bp + k0 + 32);
        }
        short8 a0 = *(const short8*)&As[wm + lrow][lq * 8];
        short8 a1 = *(const short8*)&As[wm + 16 + lrow][lq * 8];
        short8 b0 = *(const short8*)&Bs[wn + lrow][lq * 8];
        short8 b1 = *(const short8*)&Bs[wn + 16 + lrow][lq * 8];
        acc00 = __builtin_amdgcn_mfma_f32_16x16x32_bf16(a0, b0, acc00, 0, 0, 0);
        acc01 = __builtin_amdgcn_mfma_f32_16x16x32_bf16(a0, b1, acc01, 0, 0, 0);
        acc10 = __builtin_amdgcn_mfma_f32_16x16x32_bf16(a1, b0, acc10, 0, 0, 0);
        acc11 = __builtin_amdgcn_mfma_f32_16x16x32_bf16(a1, b1, acc11, 0, 0, 0);
        __syncthreads();
    }
    float* out = P + (size_t)blockIdx.z * M * N;
#pragma unroll
    for (int mi = 0; mi < 2; ++mi)
#pragma unroll
        for (int ni = 0; ni < 2; ++ni) {
            floatx4 a = mi == 0 ? (ni == 0 ? acc00 : acc01) : (ni == 0 ? acc10 : acc11);
#pragma unroll
            for (int r = 0; r < 4; ++r) {
                int grow = bm + wm + mi * 16 + lq * 4 + r;
                int gcol = bn + wn + ni * 16 + lrow;
                out[(size_t)grow * N + gcol] = a[r];
            }
        }
}

// ---- fused: split-reduce (N=256) + bf16 cast + per-head src/dst scores, block/row ----
__global__ __launch_bounds__(256) void k_red_scores(const float* __restrict__ P, int nsplit,
        const float* __restrict__ asrc, const float* __restrict__ adst,
        unsigned short* __restrict__ HPb, float* __restrict__ SRC, float* __restrict__ DST) {
    int row = blockIdx.x, tid = threadIdx.x;
    float v = P[(size_t)row * 256 + tid];
    for (int sp = 1; sp < nsplit; ++sp)
        v += P[(size_t)sp * 1048576 + (size_t)row * 256 + tid];
    HPb[(size_t)row * 256 + tid] = f2bf(v);
    float s = v * asrc[tid], d = v * adst[tid];
    for (int o = 16; o; o >>= 1) { s += __shfl_xor(s, o); d += __shfl_xor(d, o); }
    if ((tid & 31) == 0) {
        int h = tid >> 5;
        SRC[row * 8 + h] = s;
        DST[row * 8 + h] = d;
    }
}

// ------- attn layers 0/1: out = elu(agg + X); optional fused layer-2 scores -------
__global__ __launch_bounds__(256) void k_attn_small_f(const unsigned short* __restrict__ hp,
        const float* __restrict__ src, const float* __restrict__ dst,
        const int* __restrict__ nbr, const int* __restrict__ cnts,
        const float* __restrict__ X, float* __restrict__ Hout,
        unsigned short* __restrict__ Hb,
        const float* __restrict__ WS2, const float* __restrict__ WD2,
        float* __restrict__ SRC2, float* __restrict__ DST2) {
    int row = blockIdx.x;
    int tid = threadIdx.x;
    int rb = row & ~(S_ - 1);
    __shared__ int nb[MAXDEG];
    __shared__ float ss[8];
    __shared__ float ew[MAXDEG * 9];
    __shared__ float pr[4][16];
    int cnt = cnts[row];
    for (int t = tid; t < cnt; t += 256) nb[t] = nbr[row * MAXDEG + t];
    if (tid < 8) ss[tid] = src[row * H_ + tid];
    __syncthreads();
    for (int idx = tid; idx < cnt * 8; idx += 256) {
        int n = idx >> 3, h = idx & 7;
        int j = nb[n];
        float e = ss[h] + dst[(rb + j) * H_ + h];
        ew[n * 9 + h] = e > 0.f ? e : LRELU_ALPHA * e;
    }
    __syncthreads();
    {
        int lane = tid & 63, wv = tid >> 6;
        int h = wv * 2 + (lane >> 5), sub = lane & 31;
        float m = -1e30f;
        for (int n = sub; n < cnt; n += 32) m = fmaxf(m, ew[n * 9 + h]);
        for (int o = 16; o; o >>= 1) m = fmaxf(m, __shfl_xor(m, o));
        float s = 0.f;
        for (int n = sub; n < cnt; n += 32) {
            float v = __expf(ew[n * 9 + h] - m); ew[n * 9 + h] = v; s += v;
        }
        for (int o = 16; o; o >>= 1) s += __shfl_xor(s, o);
        float inv = s > 0.f ? 1.f / s : 0.f;
        for (int n = sub; n < cnt; n += 32) ew[n * 9 + h] *= inv;
    }
    __syncthreads();
    int h = tid >> 5;
    float acc0 = 0.f, acc1 = 0.f;
    const unsigned short* hpb = hp + (size_t)rb * 256;
    int n = 0;
    for (; n + 1 < cnt; n += 2) {
        int j0 = nb[n], j1 = nb[n + 1];
        float w0 = ew[n * 9 + h], w1 = ew[(n + 1) * 9 + h];
        acc0 += w0 * bf2f(hpb[(size_t)j0 * 256 + tid]);
        acc1 += w1 * bf2f(hpb[(size_t)j1 * 256 + tid]);
    }
    if (n < cnt) acc0 += ew[n * 9 + h] * bf2f(hpb[(size_t)nb[n] * 256 + tid]);
    float ov = acc0 + acc1 + X[(size_t)row * 256 + tid];
    ov = ov > 0.f ? ov : (__expf(ov) - 1.f);
    Hout[(size_t)row * 256 + tid] = ov;
    Hb[(size_t)row * 256 + tid] = f2bf(ov);
    // fused layer-2 scores: src2/dst2[row][h] = dot(ov_row, WS2/WD2[h])
    if (WS2 != nullptr) {
        int lane = tid & 63, wv = tid >> 6;
#pragma unroll
        for (int hh = 0; hh < 8; ++hh) {
            float sP = ov * WS2[hh * 256 + tid];
            float dP = ov * WD2[hh * 256 + tid];
            for (int o = 32; o; o >>= 1) { sP += __shfl_xor(sP, o); dP += __shfl_xor(dP, o); }
            if (lane == 0) { pr[wv][hh * 2] = sP; pr[wv][hh * 2 + 1] = dP; }
        }
        __syncthreads();
        if (tid < 16) {
            float tv = pr[0][tid] + pr[1][tid] + pr[2][tid] + pr[3][tid];
            if ((tid & 1) == 0) SRC2[row * 8 + (tid >> 1)] = tv;
            else                DST2[row * 8 + (tid >> 1)] = tv;
        }
    }
}

// ------- layer-2 aggregation over H rows: Ycat[row][h*256+k] = (attn_h/8 @ H)[k] -------
__global__ __launch_bounds__(256) void k_attn_Y(const unsigned short* __restrict__ Hb,
        const float* __restrict__ src2, const float* __restrict__ dst2,
        const int* __restrict__ nbr, const int* __restrict__ cnts,
        unsigned short* __restrict__ Ycat) {
    int row = blockIdx.x;
    int tid = threadIdx.x;
    int rb = row & ~(S_ - 1);
    __shared__ int nb[MAXDEG];
    __shared__ float ss[8];
    __shared__ float ew[MAXDEG * 10];
    int cnt = cnts[row];
    for (int t = tid; t < cnt; t += 256) nb[t] = nbr[row * MAXDEG + t];
    if (tid < 8) ss[tid] = src2[row * H_ + tid];
    __syncthreads();
    for (int idx = tid; idx < cnt * 8; idx += 256) {
        int n = idx >> 3, h = idx & 7;
        int j = nb[n];
        float e = ss[h] + dst2[(rb + j) * H_ + h];
        ew[n * 10 + h] = e > 0.f ? e : LRELU_ALPHA * e;
    }
    __syncthreads();
    {
        int lane = tid & 63, wv = tid >> 6;
        int h = wv * 2 + (lane >> 5), sub = lane & 31;
        float m = -1e30f;
        for (int n = sub; n < cnt; n += 32) m = fmaxf(m, ew[n * 10 + h]);
        for (int o = 16; o; o >>= 1) m = fmaxf(m, __shfl_xor(m, o));
        float s = 0.f;
        for (int n = sub; n < cnt; n += 32) {
            float v = __expf(ew[n * 10 + h] - m); ew[n * 10 + h] = v; s += v;
        }
        for (int o = 16; o; o >>= 1) s += __shfl_xor(s, o);
        float inv = s > 0.f ? 0.125f / s : 0.f;
        for (int n = sub; n < cnt; n += 32) ew[n * 10 + h] *= inv;
    }
    __syncthreads();
    float acc[8] = {0.f,0.f,0.f,0.f,0.f,0.f,0.f,0.f};
    for (int n = 0; n < cnt; ++n) {
        int j = nb[n];
        float v = bf2f(Hb[(size_t)(rb + j) * 256 + tid]);
        const float2* w = (const float2*)&ew[n * 10];
        float2 w01 = w[0], w23 = w[1], w45 = w[2], w67 = w[3];
        acc[0] += w01.x * v; acc[1] += w01.y * v;
        acc[2] += w23.x * v; acc[3] += w23.y * v;
        acc[4] += w45.x * v; acc[5] += w45.y * v;
        acc[6] += w67.x * v; acc[7] += w67.y * v;
    }
#pragma unroll
    for (int h = 0; h < 8; ++h)
        Ycat[(size_t)row * 2048 + h * 256 + tid] = f2bf(acc[h]);
}

// ------- 8-way split reduce + residual + LayerNorm, fp32 + bf16 out -------
__global__ __launch_bounds__(256) void k_ln_red(const float* __restrict__ P, int nsplit,
        const float* __restrict__ Hres, const float* __restrict__ g,
        const float* __restrict__ bta, float* __restrict__ HLN,
        unsigned short* __restrict__ HLNb) {
    int row = blockIdx.x * 4 + (threadIdx.x >> 6);
    int lane = threadIdx.x & 63;
    float4 v = ((const float4*)(Hres + (size_t)row * 256))[lane];
    for (int sp = 0; sp < nsplit; ++sp) {
        float4 p = ((const float4*)(P + (size_t)sp * 1048576 + (size_t)row * 256))[lane];
        v.x += p.x; v.y += p.y; v.z += p.z; v.w += p.w;
    }
    float s = v.x + v.y + v.z + v.w;
    float q = v.x * v.x + v.y * v.y + v.z * v.z + v.w * v.w;
    for (int o = 32; o; o >>= 1) { s += __shfl_xor(s, o); q += __shfl_xor(q, o); }
    float mu = s * (1.f / 256.f);
    float var = q * (1.f / 256.f) - mu * mu;
    if (var < 0.f) var = 0.f;
    float rs = rsqrtf(var + 1e-5f);
    float4 gg = ((const float4*)g)[lane];
    float4 bb = ((const float4*)bta)[lane];
    float4 o;
    o.x = (v.x - mu) * rs * gg.x + bb.x;
    o.y = (v.y - mu) * rs * gg.y + bb.y;
    o.z = (v.z - mu) * rs * gg.z + bb.z;
    o.w = (v.w - mu) * rs * gg.w + bb.w;
    ((float4*)(HLN + (size_t)row * 256))[lane] = o;
    ushort4 ob; ob.x = f2bf(o.x); ob.y = f2bf(o.y); ob.z = f2bf(o.z); ob.w = f2bf(o.w);
    ((ushort4*)(HLNb + (size_t)row * 256))[lane] = ob;
}

// ---------------- split reduce + bias + gelu -> bf16 ----------------
__global__ void k_red_gelu(const float* __restrict__ P, const float* __restrict__ b1,
                           unsigned short* __restrict__ out, int n, int nsplit, int cmask4) {
    int i = blockIdx.x * blockDim.x + threadIdx.x;
    if (i >= (n >> 2)) return;
    float4 s = ((const float4*)P)[i];
    for (int sp = 1; sp < nsplit; ++sp) {
        float4 v = ((const float4*)(P + (size_t)sp * n))[i];
        s.x += v.x; s.y += v.y; s.z += v.z; s.w += v.w;
    }
    float4 bb = ((const float4*)b1)[i & cmask4];
    float xs[4] = {s.x + bb.x, s.y + bb.y, s.z + bb.z, s.w + bb.w};
    ushort4 u;
    unsigned short* up = (unsigned short*)&u;
#pragma unroll
    for (int q = 0; q < 4; ++q) {
        float x = xs[q];
        float t = tanhf(0.7978845608028654f * (x + 0.044715f * x * x * x));
        up[q] = f2bf(0.5f * x * (1.f + t));
    }
    ((ushort4*)out)[i] = u;
}

// ---------------- split reduce + residual + bias -> fp32 (final) ----------------
__global__ void k_red_final(const float* __restrict__ P, const float* __restrict__ HLN,
                            const float* __restrict__ b2, float* __restrict__ out,
                            int n, int nsplit) {
    int i = blockIdx.x * blockDim.x + threadIdx.x;
    if (i >= (n >> 2)) return;
    float4 s = ((const float4*)HLN)[i];
    float4 bb = ((const float4*)b2)[i & 63];
    s.x += bb.x; s.y += bb.y; s.z += bb.z; s.w += bb.w;
    for (int sp = 0; sp < nsplit; ++sp) {
        float4 v = ((const float4*)(P + (size_t)sp * n))[i];
        s.x += v.x; s.y += v.y; s.z += v.z; s.w += v.w;
    }
    ((float4*)out)[i] = s;
}

extern "C" void kernel_launch(void* const* d_in, const int* in_sizes, int n_in,
                              void* d_out, int out_size, void* d_ws, size_t ws_size,
                              hipStream_t stream) {
    const float* adj   = (const float*)d_in[0];
    const float* x     = (const float*)d_in[1];
    const float* W0    = (const float*)d_in[2];
    const float* as0   = (const float*)d_in[3];
    const float* ad0   = (const float*)d_in[4];
    const float* W1    = (const float*)d_in[5];
    const float* as1   = (const float*)d_in[6];
    const float* ad1   = (const float*)d_in[7];
    const float* W2    = (const float*)d_in[8];
    const float* as2   = (const float*)d_in[9];
    const float* ad2   = (const float*)d_in[10];
    const float* ln_g  = (const float*)d_in[11];
    const float* ln_b  = (const float*)d_in[12];
    const float* ff_w1 = (const float*)d_in[13];
    const float* ff_b1 = (const float*)d_in[14];
    const float* ff_w2 = (const float*)d_in[15];
    const float* ff_b2 = (const float*)d_in[16];

    float* ws = (float*)d_ws;
    float* H    = ws;                          // [4096,256] f32
    float* HLN  = ws + 1048576;                // [4096,256] f32
    unsigned short* Ycat = (unsigned short*)(ws + 2097152);   // [4096,2048] bf16
    unsigned short* HPb  = (unsigned short*)(ws + 6291456);   // [4096,256] bf16
    unsigned short* xb   = (unsigned short*)(ws + 6815744);
    unsigned short* Hb   = (unsigned short*)(ws + 7340032);
    unsigned short* HLNb = (unsigned short*)(ws + 7864320);
    unsigned short* MIDb = (unsigned short*)(ws + 8388608);   // [4096,512] bf16
    unsigned short* W0t  = (unsigned short*)(ws + 9437184);   // [256,256]
    unsigned short* W1t  = (unsigned short*)(ws + 9469952);
    unsigned short* W2t  = (unsigned short*)(ws + 9502720);   // [256,2048]
    unsigned short* F1t  = (unsigned short*)(ws + 9764864);   // [512,256]
    unsigned short* F2t  = (unsigned short*)(ws + 9830400);   // [256,512]
    float* WS2  = ws + 9895936;                // [8,256]
    float* WD2  = ws + 9897984;                // [8,256]
    float* SRC  = ws + 9900032;                // [4096,8]
    float* DST  = ws + 9932800;
    float* SRC2 = ws + 9965568;                // [4096,8] layer-2 scores
    float* DST2 = ws + 9998336;
    int*   NBR  = (int*)(ws + 10031104);       // [4096,128]
    int*   CNT  = (int*)(ws + 10555392);
    float* PP   = ws + 12582912;               // split-K partials, up to [8][4096][256] f32

    // one prep kernel: CSR + casts + transposes + wvec2
    k_prep<<<6024, 256, 0, stream>>>(x, xb, W0, W0t, W1, W1t, W2, W2t,
                                     ff_w1, F1t, ff_w2, F2t, as2, ad2, WS2, WD2,
                                     adj, NBR, CNT);

    // ---- GAT layer 0 ----
    k_gemm_mfma<<<dim3(4, 64, 4), 256, 0, stream>>>(xb, W0t, PP, 4096, 256, 256, 64);
    k_red_scores<<<4096, 256, 0, stream>>>(PP, 4, as0, ad0, HPb, SRC, DST);
    k_attn_small_f<<<4096, 256, 0, stream>>>(HPb, SRC, DST, NBR, CNT, x, H, Hb,
                                             nullptr, nullptr, nullptr, nullptr);

    // ---- GAT layer 1 (layer-2 scores fused into epilogue) ----
    k_gemm_mfma<<<dim3(4, 64, 4), 256, 0, stream>>>(Hb, W1t, PP, 4096, 256, 256, 64);
    k_red_scores<<<4096, 256, 0, stream>>>(PP, 4, as1, ad1, HPb, SRC, DST);
    k_attn_small_f<<<4096, 256, 0, stream>>>(HPb, SRC, DST, NBR, CNT, H, H, Hb,
                                             WS2, WD2, SRC2, DST2);

    // ---- GAT layer 2: aggregate H, GEMM with W2 (split 8), LN fused ----
    k_attn_Y<<<4096, 256, 0, stream>>>(Hb, SRC2, DST2, NBR, CNT, Ycat);
    k_gemm_mfma<<<dim3(4, 64, 8), 256, 0, stream>>>(Ycat, W2t, PP, 4096, 256, 2048, 256);
    k_ln_red<<<1024, 256, 0, stream>>>(PP, 8, H, ln_g, ln_b, HLN, HLNb);

    // ---- FFN ----
    k_gemm_mfma<<<dim3(8, 64, 2), 256, 0, stream>>>(HLNb, F1t, PP, 4096, 512, 256, 128);
    k_red_gelu<<<2048, 256, 0, stream>>>(PP, ff_b1, MIDb, 2097152, 2, 127);
    k_gemm_mfma<<<dim3(4, 64, 4), 256, 0, stream>>>(MIDb, F2t, PP, 4096, 256, 512, 128);
    k_red_final<<<1024, 256, 0, stream>>>(PP, HLN, ff_b2, (float*)d_out, 1048576, 4);
}

// Round 9
// 265.790 us; speedup vs baseline: 1.1101x; 1.0469x over previous
//
#include <hip/hip_runtime.h>
#include <hip/hip_bf16.h>

#define B_ 4
#define S_ 1024
#define D_ 256
#define H_ 8
#define LRELU_ALPHA 0.2f
#define MAXDEG 128

typedef __attribute__((ext_vector_type(8))) short short8;
typedef __attribute__((ext_vector_type(4))) float floatx4;

__device__ __forceinline__ float bf2f(unsigned short u) {
    union { unsigned int i; float f; } c; c.i = ((unsigned int)u) << 16; return c.f;
}
__device__ __forceinline__ unsigned short f2bf(float f) {
    union { float f; unsigned int u; } c; c.f = f;
    unsigned int r = (c.u + 0x7FFF + ((c.u >> 16) & 1)) >> 16;
    return (unsigned short)r;
}

// ---------- fused prep: CSR + x-cast + weight transposes + wvec2, one launch ----------
__device__ void castT_body(const float* __restrict__ W, unsigned short* __restrict__ out,
                           int K, int N, int k0, int n0, float (*t)[33], int tid) {
    int tx = tid & 31, ty = tid >> 5;
#pragma unroll
    for (int i = 0; i < 4; ++i)
        t[ty + 8 * i][tx] = W[(size_t)(k0 + ty + 8 * i) * N + n0 + tx];
    __syncthreads();
#pragma unroll
    for (int i = 0; i < 4; ++i)
        out[(size_t)(n0 + ty + 8 * i) * K + k0 + tx] = f2bf(t[tx][ty + 8 * i]);
}

__global__ __launch_bounds__(256) void k_prep(
        const float* __restrict__ x, unsigned short* __restrict__ xb,
        const float* __restrict__ W0, unsigned short* __restrict__ W0t,
        const float* __restrict__ W1, unsigned short* __restrict__ W1t,
        const float* __restrict__ W2, unsigned short* __restrict__ W2t,
        const float* __restrict__ F1, unsigned short* __restrict__ F1t,
        const float* __restrict__ F2, unsigned short* __restrict__ F2t,
        const float* __restrict__ as2, const float* __restrict__ ad2,
        float* __restrict__ WS2, float* __restrict__ WD2,
        const float* __restrict__ adj, int* __restrict__ nbr, int* __restrict__ cnt) {
    __shared__ float t[32][33];
    __shared__ int c;
    int b = blockIdx.x, tid = threadIdx.x;
    if (b < 1024) {                       // x -> bf16
        int i = b * 256 + tid;
        float4 v = ((const float4*)x)[i];
        ushort4 u; u.x = f2bf(v.x); u.y = f2bf(v.y); u.z = f2bf(v.z); u.w = f2bf(v.w);
        ((ushort4*)xb)[i] = u;
    } else if (b < 1088) {                // W0^T
        int i = b - 1024; castT_body(W0, W0t, 256, 256, (i & 7) * 32, (i >> 3) * 32, t, tid);
    } else if (b < 1152) {                // W1^T
        int i = b - 1088; castT_body(W1, W1t, 256, 256, (i & 7) * 32, (i >> 3) * 32, t, tid);
    } else if (b < 1664) {                // W2 per-head transpose
        int i = b - 1152;
        int k0 = (i & 7) * 32, d0 = ((i >> 3) & 7) * 32, h = i >> 6;
        int tx = tid & 31, ty = tid >> 5;
#pragma unroll
        for (int q = 0; q < 4; ++q)
            t[ty + 8 * q][tx] = W2[(size_t)(k0 + ty + 8 * q) * 2048 + h * 256 + d0 + tx];
        __syncthreads();
#pragma unroll
        for (int q = 0; q < 4; ++q)
            W2t[(size_t)(d0 + ty + 8 * q) * 2048 + h * 256 + k0 + tx] = f2bf(t[tx][ty + 8 * q]);
    } else if (b < 1792) {                // ff_w1^T
        int i = b - 1664; castT_body(F1, F1t, 256, 512, (i & 7) * 32, (i >> 3) * 32, t, tid);
    } else if (b < 1920) {                // ff_w2^T
        int i = b - 1792; castT_body(F2, F2t, 512, 256, (i & 15) * 32, (i >> 4) * 32, t, tid);
    } else if (b < 1928) {                // wvec2
        int h = b - 1920, k = tid;
        const float* wrow = W2 + (size_t)k * 2048 + h * 256;
        float s = 0.f, d = 0.f;
        for (int dd = 0; dd < 256; ++dd) {
            float w = wrow[dd];
            s += w * as2[h * 256 + dd];
            d += w * ad2[h * 256 + dd];
        }
        WS2[h * 256 + k] = s;
        WD2[h * 256 + k] = d;
    } else {                              // CSR build
        int row = b - 1928;
        if (tid == 0) c = 0;
        __syncthreads();
        for (int j = tid; j < S_; j += 256) {
            if (adj[(size_t)row * S_ + j] > 0.f) {
                int s = atomicAdd(&c, 1);
                if (s < MAXDEG) nbr[row * MAXDEG + s] = j;
            }
        }
        __syncthreads();
        if (tid == 0) cnt[row] = c < MAXDEG ? c : MAXDEG;
    }
}

// ------- wide-tile split-K MFMA GEMM: tile 64M x 256N, 4 waves x (4x4 accs) -------
// grid (N/256, M/64, nsplit); Kc = K/nsplit. P[z][M][N] fp32 partials.
__global__ __launch_bounds__(256) void k_gemm_wide(const unsigned short* __restrict__ A,
        const unsigned short* __restrict__ Bt, float* __restrict__ P,
        int M, int N, int K, int Kc) {
    __shared__ unsigned short As[64][40];
    __shared__ unsigned short Bs[256][40];
    int tid = threadIdx.x;
    int bm = blockIdx.y * 64, bn = blockIdx.x * 256;
    int kbeg = blockIdx.z * Kc, kend = kbeg + Kc;
    int lane = tid & 63, wv = tid >> 6;
    int lrow = lane & 15, lq = lane >> 4;
    floatx4 acc[4][4] = {};
    int sm = tid >> 2, skq = (tid & 3) * 8;
    const unsigned short* Ap = A + (size_t)(bm + sm) * K + skq;
    const unsigned short* Bp0 = Bt + (size_t)(bn + sm) * K + skq;
    const unsigned short* Bp1 = Bp0 + (size_t)64 * K;
    const unsigned short* Bp2 = Bp0 + (size_t)128 * K;
    const unsigned short* Bp3 = Bp0 + (size_t)192 * K;
    short8 av  = *(const short8*)(Ap + kbeg);
    short8 bv0 = *(const short8*)(Bp0 + kbeg);
    short8 bv1 = *(const short8*)(Bp1 + kbeg);
    short8 bv2 = *(const short8*)(Bp2 + kbeg);
    short8 bv3 = *(const short8*)(Bp3 + kbeg);
    for (int k0 = kbeg; k0 < kend; k0 += 32) {
        *(short8*)&As[sm][skq]        = av;
        *(short8*)&Bs[sm][skq]        = bv0;
        *(short8*)&Bs[sm + 64][skq]   = bv1;
        *(short8*)&Bs[sm + 128][skq]  = bv2;
        *(short8*)&Bs[sm + 192][skq]  = bv3;
        __syncthreads();
        if (k0 + 32 < kend) {
            av  = *(const short8*)(Ap + k0 + 32);
            bv0 = *(const short8*)(Bp0 + k0 + 32);
            bv1 = *(const short8*)(Bp1 + k0 + 32);
            bv2 = *(const short8*)(Bp2 + k0 + 32);
            bv3 = *(const short8*)(Bp3 + k0 + 32);
        }
        short8 aF[4], bF[4];
#pragma unroll
        for (int mi = 0; mi < 4; ++mi)
            aF[mi] = *(const short8*)&As[mi * 16 + lrow][lq * 8];
#pragma unroll
        for (int ni = 0; ni < 4; ++ni)
            bF[ni] = *(const short8*)&Bs[wv * 64 + ni * 16 + lrow][lq * 8];
#pragma unroll
        for (int mi = 0; mi < 4; ++mi)
#pragma unroll
            for (int ni = 0; ni < 4; ++ni)
                acc[mi][ni] = __builtin_amdgcn_mfma_f32_16x16x32_bf16(aF[mi], bF[ni], acc[mi][ni], 0, 0, 0);
        __syncthreads();
    }
    float* out = P + (size_t)blockIdx.z * M * N;
#pragma unroll
    for (int mi = 0; mi < 4; ++mi)
#pragma unroll
        for (int ni = 0; ni < 4; ++ni)
#pragma unroll
            for (int r = 0; r < 4; ++r) {
                int grow = bm + mi * 16 + lq * 4 + r;
                int gcol = bn + wv * 64 + ni * 16 + lrow;
                out[(size_t)grow * N + gcol] = acc[mi][ni][r];
            }
}

// ---- fused: split-reduce (N=256) + bf16 cast + per-head src/dst scores, block/row ----
__global__ __launch_bounds__(256) void k_red_scores(const float* __restrict__ P, int nsplit,
        const float* __restrict__ asrc, const float* __restrict__ adst,
        unsigned short* __restrict__ HPb, float* __restrict__ SRC, float* __restrict__ DST) {
    int row = blockIdx.x, tid = threadIdx.x;
    float v = P[(size_t)row * 256 + tid];
    for (int sp = 1; sp < nsplit; ++sp)
        v += P[(size_t)sp * 1048576 + (size_t)row * 256 + tid];
    HPb[(size_t)row * 256 + tid] = f2bf(v);
    float s = v * asrc[tid], d = v * adst[tid];
    for (int o = 16; o; o >>= 1) { s += __shfl_xor(s, o); d += __shfl_xor(d, o); }
    if ((tid & 31) == 0) {
        int h = tid >> 5;
        SRC[row * 8 + h] = s;
        DST[row * 8 + h] = d;
    }
}

// ------- attn layers 0/1: out = elu(agg + X); optional fused layer-2 scores -------
__global__ __launch_bounds__(256) void k_attn_small_f(const unsigned short* __restrict__ hp,
        const float* __restrict__ src, const float* __restrict__ dst,
        const int* __restrict__ nbr, const int* __restrict__ cnts,
        const float* __restrict__ X, float* __restrict__ Hout,
        unsigned short* __restrict__ Hb,
        const float* __restrict__ WS2, const float* __restrict__ WD2,
        float* __restrict__ SRC2, float* __restrict__ DST2) {
    int row = blockIdx.x;
    int tid = threadIdx.x;
    int rb = row & ~(S_ - 1);
    __shared__ int nb[MAXDEG];
    __shared__ float ss[8];
    __shared__ float ew[MAXDEG * 9];
    __shared__ float pr[4][16];
    int cnt = cnts[row];
    for (int t = tid; t < cnt; t += 256) nb[t] = nbr[row * MAXDEG + t];
    if (tid < 8) ss[tid] = src[row * H_ + tid];
    __syncthreads();
    for (int idx = tid; idx < cnt * 8; idx += 256) {
        int n = idx >> 3, h = idx & 7;
        int j = nb[n];
        float e = ss[h] + dst[(rb + j) * H_ + h];
        ew[n * 9 + h] = e > 0.f ? e : LRELU_ALPHA * e;
    }
    __syncthreads();
    {
        int lane = tid & 63, wv = tid >> 6;
        int h = wv * 2 + (lane >> 5), sub = lane & 31;
        float m = -1e30f;
        for (int n = sub; n < cnt; n += 32) m = fmaxf(m, ew[n * 9 + h]);
        for (int o = 16; o; o >>= 1) m = fmaxf(m, __shfl_xor(m, o));
        float s = 0.f;
        for (int n = sub; n < cnt; n += 32) {
            float v = __expf(ew[n * 9 + h] - m); ew[n * 9 + h] = v; s += v;
        }
        for (int o = 16; o; o >>= 1) s += __shfl_xor(s, o);
        float inv = s > 0.f ? 1.f / s : 0.f;
        for (int n = sub; n < cnt; n += 32) ew[n * 9 + h] *= inv;
    }
    __syncthreads();
    int h = tid >> 5;
    float acc0 = 0.f, acc1 = 0.f;
    const unsigned short* hpb = hp + (size_t)rb * 256;
    int n = 0;
    for (; n + 1 < cnt; n += 2) {
        int j0 = nb[n], j1 = nb[n + 1];
        float w0 = ew[n * 9 + h], w1 = ew[(n + 1) * 9 + h];
        acc0 += w0 * bf2f(hpb[(size_t)j0 * 256 + tid]);
        acc1 += w1 * bf2f(hpb[(size_t)j1 * 256 + tid]);
    }
    if (n < cnt) acc0 += ew[n * 9 + h] * bf2f(hpb[(size_t)nb[n] * 256 + tid]);
    float ov = acc0 + acc1 + X[(size_t)row * 256 + tid];
    ov = ov > 0.f ? ov : (__expf(ov) - 1.f);
    Hout[(size_t)row * 256 + tid] = ov;
    Hb[(size_t)row * 256 + tid] = f2bf(ov);
    if (WS2 != nullptr) {
        int lane = tid & 63, wv = tid >> 6;
#pragma unroll
        for (int hh = 0; hh < 8; ++hh) {
            float sP = ov * WS2[hh * 256 + tid];
            float dP = ov * WD2[hh * 256 + tid];
            for (int o = 32; o; o >>= 1) { sP += __shfl_xor(sP, o); dP += __shfl_xor(dP, o); }
            if (lane == 0) { pr[wv][hh * 2] = sP; pr[wv][hh * 2 + 1] = dP; }
        }
        __syncthreads();
        if (tid < 16) {
            float tv = pr[0][tid] + pr[1][tid] + pr[2][tid] + pr[3][tid];
            if ((tid & 1) == 0) SRC2[row * 8 + (tid >> 1)] = tv;
            else                DST2[row * 8 + (tid >> 1)] = tv;
        }
    }
}

// ------- layer-2 aggregation over H rows: Ycat[row][h*256+k] = (attn_h/8 @ H)[k] -------
__global__ __launch_bounds__(256) void k_attn_Y(const unsigned short* __restrict__ Hb,
        const float* __restrict__ src2, const float* __restrict__ dst2,
        const int* __restrict__ nbr, const int* __restrict__ cnts,
        unsigned short* __restrict__ Ycat) {
    int row = blockIdx.x;
    int tid = threadIdx.x;
    int rb = row & ~(S_ - 1);
    __shared__ int nb[MAXDEG];
    __shared__ float ss[8];
    __shared__ float ew[MAXDEG * 10];
    int cnt = cnts[row];
    for (int t = tid; t < cnt; t += 256) nb[t] = nbr[row * MAXDEG + t];
    if (tid < 8) ss[tid] = src2[row * H_ + tid];
    __syncthreads();
    for (int idx = tid; idx < cnt * 8; idx += 256) {
        int n = idx >> 3, h = idx & 7;
        int j = nb[n];
        float e = ss[h] + dst2[(rb + j) * H_ + h];
        ew[n * 10 + h] = e > 0.f ? e : LRELU_ALPHA * e;
    }
    __syncthreads();
    {
        int lane = tid & 63, wv = tid >> 6;
        int h = wv * 2 + (lane >> 5), sub = lane & 31;
        float m = -1e30f;
        for (int n = sub; n < cnt; n += 32) m = fmaxf(m, ew[n * 10 + h]);
        for (int o = 16; o; o >>= 1) m = fmaxf(m, __shfl_xor(m, o));
        float s = 0.f;
        for (int n = sub; n < cnt; n += 32) {
            float v = __expf(ew[n * 10 + h] - m); ew[n * 10 + h] = v; s += v;
        }
        for (int o = 16; o; o >>= 1) s += __shfl_xor(s, o);
        float inv = s > 0.f ? 0.125f / s : 0.f;
        for (int n = sub; n < cnt; n += 32) ew[n * 10 + h] *= inv;
    }
    __syncthreads();
    float acc[8] = {0.f,0.f,0.f,0.f,0.f,0.f,0.f,0.f};
    int n = 0;
    for (; n + 1 < cnt; n += 2) {
        int j0 = nb[n], j1 = nb[n + 1];
        float v0 = bf2f(Hb[(size_t)(rb + j0) * 256 + tid]);
        float v1 = bf2f(Hb[(size_t)(rb + j1) * 256 + tid]);
        const float2* w0p = (const float2*)&ew[n * 10];
        const float2* w1p = (const float2*)&ew[(n + 1) * 10];
#pragma unroll
        for (int q = 0; q < 4; ++q) {
            float2 w0 = w0p[q], w1 = w1p[q];
            acc[q * 2]     += w0.x * v0 + w1.x * v1;
            acc[q * 2 + 1] += w0.y * v0 + w1.y * v1;
        }
    }
    if (n < cnt) {
        int j = nb[n];
        float v = bf2f(Hb[(size_t)(rb + j) * 256 + tid]);
        const float2* w = (const float2*)&ew[n * 10];
#pragma unroll
        for (int q = 0; q < 4; ++q) {
            float2 wq = w[q];
            acc[q * 2]     += wq.x * v;
            acc[q * 2 + 1] += wq.y * v;
        }
    }
#pragma unroll
    for (int h = 0; h < 8; ++h)
        Ycat[(size_t)row * 2048 + h * 256 + tid] = f2bf(acc[h]);
}

// ------- 8-way split reduce + residual + LayerNorm, fp32 + bf16 out -------
__global__ __launch_bounds__(256) void k_ln_red(const float* __restrict__ P, int nsplit,
        const float* __restrict__ Hres, const float* __restrict__ g,
        const float* __restrict__ bta, float* __restrict__ HLN,
        unsigned short* __restrict__ HLNb) {
    int row = blockIdx.x * 4 + (threadIdx.x >> 6);
    int lane = threadIdx.x & 63;
    float4 v = ((const float4*)(Hres + (size_t)row * 256))[lane];
    for (int sp = 0; sp < nsplit; ++sp) {
        float4 p = ((const float4*)(P + (size_t)sp * 1048576 + (size_t)row * 256))[lane];
        v.x += p.x; v.y += p.y; v.z += p.z; v.w += p.w;
    }
    float s = v.x + v.y + v.z + v.w;
    float q = v.x * v.x + v.y * v.y + v.z * v.z + v.w * v.w;
    for (int o = 32; o; o >>= 1) { s += __shfl_xor(s, o); q += __shfl_xor(q, o); }
    float mu = s * (1.f / 256.f);
    float var = q * (1.f / 256.f) - mu * mu;
    if (var < 0.f) var = 0.f;
    float rs = rsqrtf(var + 1e-5f);
    float4 gg = ((const float4*)g)[lane];
    float4 bb = ((const float4*)bta)[lane];
    float4 o;
    o.x = (v.x - mu) * rs * gg.x + bb.x;
    o.y = (v.y - mu) * rs * gg.y + bb.y;
    o.z = (v.z - mu) * rs * gg.z + bb.z;
    o.w = (v.w - mu) * rs * gg.w + bb.w;
    ((float4*)(HLN + (size_t)row * 256))[lane] = o;
    ushort4 ob; ob.x = f2bf(o.x); ob.y = f2bf(o.y); ob.z = f2bf(o.z); ob.w = f2bf(o.w);
    ((ushort4*)(HLNb + (size_t)row * 256))[lane] = ob;
}

// ---------------- split reduce + bias + gelu -> bf16 ----------------
__global__ void k_red_gelu(const float* __restrict__ P, const float* __restrict__ b1,
                           unsigned short* __restrict__ out, int n, int nsplit, int cmask4) {
    int i = blockIdx.x * blockDim.x + threadIdx.x;
    if (i >= (n >> 2)) return;
    float4 s = ((const float4*)P)[i];
    for (int sp = 1; sp < nsplit; ++sp) {
        float4 v = ((const float4*)(P + (size_t)sp * n))[i];
        s.x += v.x; s.y += v.y; s.z += v.z; s.w += v.w;
    }
    float4 bb = ((const float4*)b1)[i & cmask4];
    float xs[4] = {s.x + bb.x, s.y + bb.y, s.z + bb.z, s.w + bb.w};
    ushort4 u;
    unsigned short* up = (unsigned short*)&u;
#pragma unroll
    for (int q = 0; q < 4; ++q) {
        float x = xs[q];
        float t = tanhf(0.7978845608028654f * (x + 0.044715f * x * x * x));
        up[q] = f2bf(0.5f * x * (1.f + t));
    }
    ((ushort4*)out)[i] = u;
}

// ---------------- split reduce + residual + bias -> fp32 (final) ----------------
__global__ void k_red_final(const float* __restrict__ P, const float* __restrict__ HLN,
                            const float* __restrict__ b2, float* __restrict__ out,
                            int n, int nsplit) {
    int i = blockIdx.x * blockDim.x + threadIdx.x;
    if (i >= (n >> 2)) return;
    float4 s = ((const float4*)HLN)[i];
    float4 bb = ((const float4*)b2)[i & 63];
    s.x += bb.x; s.y += bb.y; s.z += bb.z; s.w += bb.w;
    for (int sp = 0; sp < nsplit; ++sp) {
        float4 v = ((const float4*)(P + (size_t)sp * n))[i];
        s.x += v.x; s.y += v.y; s.z += v.z; s.w += v.w;
    }
    ((float4*)out)[i] = s;
}

extern "C" void kernel_launch(void* const* d_in, const int* in_sizes, int n_in,
                              void* d_out, int out_size, void* d_ws, size_t ws_size,
                              hipStream_t stream) {
    const float* adj   = (const float*)d_in[0];
    const float* x     = (const float*)d_in[1];
    const float* W0    = (const float*)d_in[2];
    const float* as0   = (const float*)d_in[3];
    const float* ad0   = (const float*)d_in[4];
    const float* W1    = (const float*)d_in[5];
    const float* as1   = (const float*)d_in[6];
    const float* ad1   = (const float*)d_in[7];
    const float* W2    = (const float*)d_in[8];
    const float* as2   = (const float*)d_in[9];
    const float* ad2   = (const float*)d_in[10];
    const float* ln_g  = (const float*)d_in[11];
    const float* ln_b  = (const float*)d_in[12];
    const float* ff_w1 = (const float*)d_in[13];
    const float* ff_b1 = (const float*)d_in[14];
    const float* ff_w2 = (const float*)d_in[15];
    const float* ff_b2 = (const float*)d_in[16];

    float* ws = (float*)d_ws;
    float* H    = ws;                          // [4096,256] f32
    float* HLN  = ws + 1048576;                // [4096,256] f32
    unsigned short* Ycat = (unsigned short*)(ws + 2097152);   // [4096,2048] bf16
    unsigned short* HPb  = (unsigned short*)(ws + 6291456);   // [4096,256] bf16
    unsigned short* xb   = (unsigned short*)(ws + 6815744);
    unsigned short* Hb   = (unsigned short*)(ws + 7340032);
    unsigned short* HLNb = (unsigned short*)(ws + 7864320);
    unsigned short* MIDb = (unsigned short*)(ws + 8388608);   // [4096,512] bf16
    unsigned short* W0t  = (unsigned short*)(ws + 9437184);   // [256,256]
    unsigned short* W1t  = (unsigned short*)(ws + 9469952);
    unsigned short* W2t  = (unsigned short*)(ws + 9502720);   // [256,2048]
    unsigned short* F1t  = (unsigned short*)(ws + 9764864);   // [512,256]
    unsigned short* F2t  = (unsigned short*)(ws + 9830400);   // [256,512]
    float* WS2  = ws + 9895936;                // [8,256]
    float* WD2  = ws + 9897984;                // [8,256]
    float* SRC  = ws + 9900032;                // [4096,8]
    float* DST  = ws + 9932800;
    float* SRC2 = ws + 9965568;                // [4096,8] layer-2 scores
    float* DST2 = ws + 9998336;
    int*   NBR  = (int*)(ws + 10031104);       // [4096,128]
    int*   CNT  = (int*)(ws + 10555392);
    float* PP   = ws + 12582912;               // split-K partials, up to [8][4096][256] f32

    // one prep kernel: CSR + casts + transposes + wvec2
    k_prep<<<6024, 256, 0, stream>>>(x, xb, W0, W0t, W1, W1t, W2, W2t,
                                     ff_w1, F1t, ff_w2, F2t, as2, ad2, WS2, WD2,
                                     adj, NBR, CNT);

    // ---- GAT layer 0 ----
    k_gemm_wide<<<dim3(1, 64, 4), 256, 0, stream>>>(xb, W0t, PP, 4096, 256, 256, 64);
    k_red_scores<<<4096, 256, 0, stream>>>(PP, 4, as0, ad0, HPb, SRC, DST);
    k_attn_small_f<<<4096, 256, 0, stream>>>(HPb, SRC, DST, NBR, CNT, x, H, Hb,
                                             nullptr, nullptr, nullptr, nullptr);

    // ---- GAT layer 1 (layer-2 scores fused into epilogue) ----
    k_gemm_wide<<<dim3(1, 64, 4), 256, 0, stream>>>(Hb, W1t, PP, 4096, 256, 256, 64);
    k_red_scores<<<4096, 256, 0, stream>>>(PP, 4, as1, ad1, HPb, SRC, DST);
    k_attn_small_f<<<4096, 256, 0, stream>>>(HPb, SRC, DST, NBR, CNT, H, H, Hb,
                                             WS2, WD2, SRC2, DST2);

    // ---- GAT layer 2: aggregate H, GEMM with W2 (split 8), LN fused ----
    k_attn_Y<<<4096, 256, 0, stream>>>(Hb, SRC2, DST2, NBR, CNT, Ycat);
    k_gemm_wide<<<dim3(1, 64, 8), 256, 0, stream>>>(Ycat, W2t, PP, 4096, 256, 2048, 256);
    k_ln_red<<<1024, 256, 0, stream>>>(PP, 8, H, ln_g, ln_b, HLN, HLNb);

    // ---- FFN ----
    k_gemm_wide<<<dim3(2, 64, 2), 256, 0, stream>>>(HLNb, F1t, PP, 4096, 512, 256, 128);
    k_red_gelu<<<2048, 256, 0, stream>>>(PP, ff_b1, MIDb, 2097152, 2, 127);
    k_gemm_wide<<<dim3(1, 64, 4), 256, 0, stream>>>(MIDb, F2t, PP, 4096, 256, 512, 128);
    k_red_final<<<1024, 256, 0, stream>>>(PP, HLN, ff_b2, (float*)d_out, 1048576, 4);
}

// Round 10
// 265.776 us; speedup vs baseline: 1.1102x; 1.0001x over previous
//
#include <hip/hip_runtime.h>
#include <hip/hip_bf16.h>

#define B_ 4
#define S_ 1024
#define D_ 256
#define H_ 8
#define LRELU_ALPHA 0.2f
#define MAXDEG 128

typedef __attribute__((ext_vector_type(8))) short short8;
typedef __attribute__((ext_vector_type(4))) float floatx4;

__device__ __forceinline__ float bf2f(unsigned short u) {
    union { unsigned int i; float f; } c; c.i = ((unsigned int)u) << 16; return c.f;
}
__device__ __forceinline__ unsigned short f2bf(float f) {
    union { float f; unsigned int u; } c; c.f = f;
    unsigned int r = (c.u + 0x7FFF + ((c.u >> 16) & 1)) >> 16;
    return (unsigned short)r;
}

// ---------- fused prep: CSR + x-cast + weight transposes + wvec2, one launch ----------
__device__ void castT_body(const float* __restrict__ W, unsigned short* __restrict__ out,
                           int K, int N, int k0, int n0, float (*t)[33], int tid) {
    int tx = tid & 31, ty = tid >> 5;
#pragma unroll
    for (int i = 0; i < 4; ++i)
        t[ty + 8 * i][tx] = W[(size_t)(k0 + ty + 8 * i) * N + n0 + tx];
    __syncthreads();
#pragma unroll
    for (int i = 0; i < 4; ++i)
        out[(size_t)(n0 + ty + 8 * i) * K + k0 + tx] = f2bf(t[tx][ty + 8 * i]);
}

__global__ __launch_bounds__(256) void k_prep(
        const float* __restrict__ x, unsigned short* __restrict__ xb,
        const float* __restrict__ W0, unsigned short* __restrict__ W0t,
        const float* __restrict__ W1, unsigned short* __restrict__ W1t,
        const float* __restrict__ W2, unsigned short* __restrict__ W2t,
        const float* __restrict__ F1, unsigned short* __restrict__ F1t,
        const float* __restrict__ F2, unsigned short* __restrict__ F2t,
        const float* __restrict__ as2, const float* __restrict__ ad2,
        float* __restrict__ WS2, float* __restrict__ WD2,
        const float* __restrict__ adj, int* __restrict__ nbr, int* __restrict__ cnt) {
    __shared__ float t[32][33];
    __shared__ int c;
    int b = blockIdx.x, tid = threadIdx.x;
    if (b < 1024) {                       // x -> bf16
        int i = b * 256 + tid;
        float4 v = ((const float4*)x)[i];
        ushort4 u; u.x = f2bf(v.x); u.y = f2bf(v.y); u.z = f2bf(v.z); u.w = f2bf(v.w);
        ((ushort4*)xb)[i] = u;
    } else if (b < 1088) {                // W0^T
        int i = b - 1024; castT_body(W0, W0t, 256, 256, (i & 7) * 32, (i >> 3) * 32, t, tid);
    } else if (b < 1152) {                // W1^T
        int i = b - 1088; castT_body(W1, W1t, 256, 256, (i & 7) * 32, (i >> 3) * 32, t, tid);
    } else if (b < 1664) {                // W2 per-head transpose
        int i = b - 1152;
        int k0 = (i & 7) * 32, d0 = ((i >> 3) & 7) * 32, h = i >> 6;
        int tx = tid & 31, ty = tid >> 5;
#pragma unroll
        for (int q = 0; q < 4; ++q)
            t[ty + 8 * q][tx] = W2[(size_t)(k0 + ty + 8 * q) * 2048 + h * 256 + d0 + tx];
        __syncthreads();
#pragma unroll
        for (int q = 0; q < 4; ++q)
            W2t[(size_t)(d0 + ty + 8 * q) * 2048 + h * 256 + k0 + tx] = f2bf(t[tx][ty + 8 * q]);
    } else if (b < 1792) {                // ff_w1^T
        int i = b - 1664; castT_body(F1, F1t, 256, 512, (i & 7) * 32, (i >> 3) * 32, t, tid);
    } else if (b < 1920) {                // ff_w2^T
        int i = b - 1792; castT_body(F2, F2t, 512, 256, (i & 15) * 32, (i >> 4) * 32, t, tid);
    } else if (b < 1928) {                // wvec2
        int h = b - 1920, k = tid;
        const float* wrow = W2 + (size_t)k * 2048 + h * 256;
        float s = 0.f, d = 0.f;
        for (int dd = 0; dd < 256; ++dd) {
            float w = wrow[dd];
            s += w * as2[h * 256 + dd];
            d += w * ad2[h * 256 + dd];
        }
        WS2[h * 256 + k] = s;
        WD2[h * 256 + k] = d;
    } else {                              // CSR build
        int row = b - 1928;
        if (tid == 0) c = 0;
        __syncthreads();
        for (int j = tid; j < S_; j += 256) {
            if (adj[(size_t)row * S_ + j] > 0.f) {
                int s = atomicAdd(&c, 1);
                if (s < MAXDEG) nbr[row * MAXDEG + s] = j;
            }
        }
        __syncthreads();
        if (tid == 0) cnt[row] = c < MAXDEG ? c : MAXDEG;
    }
}

// ------- wide-tile split-K MFMA GEMM: tile 64M x 256N, 4 waves x (4x4 accs) -------
__global__ __launch_bounds__(256) void k_gemm_wide(const unsigned short* __restrict__ A,
        const unsigned short* __restrict__ Bt, float* __restrict__ P,
        int M, int N, int K, int Kc) {
    __shared__ unsigned short As[64][40];
    __shared__ unsigned short Bs[256][40];
    int tid = threadIdx.x;
    int bm = blockIdx.y * 64, bn = blockIdx.x * 256;
    int kbeg = blockIdx.z * Kc, kend = kbeg + Kc;
    int lane = tid & 63, wv = tid >> 6;
    int lrow = lane & 15, lq = lane >> 4;
    floatx4 acc[4][4] = {};
    int sm = tid >> 2, skq = (tid & 3) * 8;
    const unsigned short* Ap = A + (size_t)(bm + sm) * K + skq;
    const unsigned short* Bp0 = Bt + (size_t)(bn + sm) * K + skq;
    const unsigned short* Bp1 = Bp0 + (size_t)64 * K;
    const unsigned short* Bp2 = Bp0 + (size_t)128 * K;
    const unsigned short* Bp3 = Bp0 + (size_t)192 * K;
    short8 av  = *(const short8*)(Ap + kbeg);
    short8 bv0 = *(const short8*)(Bp0 + kbeg);
    short8 bv1 = *(const short8*)(Bp1 + kbeg);
    short8 bv2 = *(const short8*)(Bp2 + kbeg);
    short8 bv3 = *(const short8*)(Bp3 + kbeg);
    for (int k0 = kbeg; k0 < kend; k0 += 32) {
        *(short8*)&As[sm][skq]        = av;
        *(short8*)&Bs[sm][skq]        = bv0;
        *(short8*)&Bs[sm + 64][skq]   = bv1;
        *(short8*)&Bs[sm + 128][skq]  = bv2;
        *(short8*)&Bs[sm + 192][skq]  = bv3;
        __syncthreads();
        if (k0 + 32 < kend) {
            av  = *(const short8*)(Ap + k0 + 32);
            bv0 = *(const short8*)(Bp0 + k0 + 32);
            bv1 = *(const short8*)(Bp1 + k0 + 32);
            bv2 = *(const short8*)(Bp2 + k0 + 32);
            bv3 = *(const short8*)(Bp3 + k0 + 32);
        }
        short8 aF[4], bF[4];
#pragma unroll
        for (int mi = 0; mi < 4; ++mi)
            aF[mi] = *(const short8*)&As[mi * 16 + lrow][lq * 8];
#pragma unroll
        for (int ni = 0; ni < 4; ++ni)
            bF[ni] = *(const short8*)&Bs[wv * 64 + ni * 16 + lrow][lq * 8];
#pragma unroll
        for (int mi = 0; mi < 4; ++mi)
#pragma unroll
            for (int ni = 0; ni < 4; ++ni)
                acc[mi][ni] = __builtin_amdgcn_mfma_f32_16x16x32_bf16(aF[mi], bF[ni], acc[mi][ni], 0, 0, 0);
        __syncthreads();
    }
    float* out = P + (size_t)blockIdx.z * M * N;
#pragma unroll
    for (int mi = 0; mi < 4; ++mi)
#pragma unroll
        for (int ni = 0; ni < 4; ++ni)
#pragma unroll
            for (int r = 0; r < 4; ++r) {
                int grow = bm + mi * 16 + lq * 4 + r;
                int gcol = bn + wv * 64 + ni * 16 + lrow;
                out[(size_t)grow * N + gcol] = acc[mi][ni][r];
            }
}

// ---- fused: split-reduce (N=256) + bf16 cast + per-head src/dst scores, block/row ----
__global__ __launch_bounds__(256) void k_red_scores(const float* __restrict__ P, int nsplit,
        const float* __restrict__ asrc, const float* __restrict__ adst,
        unsigned short* __restrict__ HPb, float* __restrict__ SRC, float* __restrict__ DST) {
    int row = blockIdx.x, tid = threadIdx.x;
    float v = P[(size_t)row * 256 + tid];
    for (int sp = 1; sp < nsplit; ++sp)
        v += P[(size_t)sp * 1048576 + (size_t)row * 256 + tid];
    HPb[(size_t)row * 256 + tid] = f2bf(v);
    float s = v * asrc[tid], d = v * adst[tid];
    for (int o = 16; o; o >>= 1) { s += __shfl_xor(s, o); d += __shfl_xor(d, o); }
    if ((tid & 31) == 0) {
        int h = tid >> 5;
        SRC[row * 8 + h] = s;
        DST[row * 8 + h] = d;
    }
}

// ------- attn layers 0/1: out = elu(agg + X); optional fused layer-2 scores -------
__global__ __launch_bounds__(256) void k_attn_small_f(const unsigned short* __restrict__ hp,
        const float* __restrict__ src, const float* __restrict__ dst,
        const int* __restrict__ nbr, const int* __restrict__ cnts,
        const float* __restrict__ X, float* __restrict__ Hout,
        unsigned short* __restrict__ Hb,
        const float* __restrict__ WS2, const float* __restrict__ WD2,
        float* __restrict__ SRC2, float* __restrict__ DST2) {
    int row = blockIdx.x;
    int tid = threadIdx.x;
    int rb = row & ~(S_ - 1);
    __shared__ int nb[MAXDEG];
    __shared__ float ss[8];
    __shared__ float ew[MAXDEG * 9];
    __shared__ float pr[4][16];
    int cnt = cnts[row];
    for (int t = tid; t < cnt; t += 256) nb[t] = nbr[row * MAXDEG + t];
    if (tid < 8) ss[tid] = src[row * H_ + tid];
    __syncthreads();
    for (int idx = tid; idx < cnt * 8; idx += 256) {
        int n = idx >> 3, h = idx & 7;
        int j = nb[n];
        float e = ss[h] + dst[(rb + j) * H_ + h];
        ew[n * 9 + h] = e > 0.f ? e : LRELU_ALPHA * e;
    }
    __syncthreads();
    {
        int lane = tid & 63, wv = tid >> 6;
        int h = wv * 2 + (lane >> 5), sub = lane & 31;
        float m = -1e30f;
        for (int n = sub; n < cnt; n += 32) m = fmaxf(m, ew[n * 9 + h]);
        for (int o = 16; o; o >>= 1) m = fmaxf(m, __shfl_xor(m, o));
        float s = 0.f;
        for (int n = sub; n < cnt; n += 32) {
            float v = __expf(ew[n * 9 + h] - m); ew[n * 9 + h] = v; s += v;
        }
        for (int o = 16; o; o >>= 1) s += __shfl_xor(s, o);
        float inv = s > 0.f ? 1.f / s : 0.f;
        for (int n = sub; n < cnt; n += 32) ew[n * 9 + h] *= inv;
    }
    __syncthreads();
    int h = tid >> 5;
    float acc0 = 0.f, acc1 = 0.f, acc2 = 0.f, acc3 = 0.f;
    const unsigned short* hpb = hp + (size_t)rb * 256;
    int n = 0;
    for (; n + 3 < cnt; n += 4) {
        int j0 = nb[n], j1 = nb[n + 1], j2 = nb[n + 2], j3 = nb[n + 3];
        float w0 = ew[n * 9 + h], w1 = ew[(n + 1) * 9 + h];
        float w2 = ew[(n + 2) * 9 + h], w3 = ew[(n + 3) * 9 + h];
        acc0 += w0 * bf2f(hpb[(size_t)j0 * 256 + tid]);
        acc1 += w1 * bf2f(hpb[(size_t)j1 * 256 + tid]);
        acc2 += w2 * bf2f(hpb[(size_t)j2 * 256 + tid]);
        acc3 += w3 * bf2f(hpb[(size_t)j3 * 256 + tid]);
    }
    for (; n < cnt; ++n)
        acc0 += ew[n * 9 + h] * bf2f(hpb[(size_t)nb[n] * 256 + tid]);
    float ov = (acc0 + acc1) + (acc2 + acc3) + X[(size_t)row * 256 + tid];
    ov = ov > 0.f ? ov : (__expf(ov) - 1.f);
    Hout[(size_t)row * 256 + tid] = ov;
    Hb[(size_t)row * 256 + tid] = f2bf(ov);
    if (WS2 != nullptr) {
        int lane = tid & 63, wv = tid >> 6;
#pragma unroll
        for (int hh = 0; hh < 8; ++hh) {
            float sP = ov * WS2[hh * 256 + tid];
            float dP = ov * WD2[hh * 256 + tid];
            for (int o = 32; o; o >>= 1) { sP += __shfl_xor(sP, o); dP += __shfl_xor(dP, o); }
            if (lane == 0) { pr[wv][hh * 2] = sP; pr[wv][hh * 2 + 1] = dP; }
        }
        __syncthreads();
        if (tid < 16) {
            float tv = pr[0][tid] + pr[1][tid] + pr[2][tid] + pr[3][tid];
            if ((tid & 1) == 0) SRC2[row * 8 + (tid >> 1)] = tv;
            else                DST2[row * 8 + (tid >> 1)] = tv;
        }
    }
}

// ------- layer-2 aggregation: thread = 2 dims x 4 heads; ew pitch 8 (b128 reads) -------
__global__ __launch_bounds__(256) void k_attn_Y(const unsigned short* __restrict__ Hb,
        const float* __restrict__ src2, const float* __restrict__ dst2,
        const int* __restrict__ nbr, const int* __restrict__ cnts,
        unsigned short* __restrict__ Ycat) {
    int row = blockIdx.x;
    int tid = threadIdx.x;
    int rb = row & ~(S_ - 1);
    __shared__ int nb[MAXDEG];
    __shared__ float ss[8];
    __shared__ float ew[MAXDEG * 8];    // pitch 8: 16B-aligned quads for b128 broadcast
    int cnt = cnts[row];
    for (int t = tid; t < cnt; t += 256) nb[t] = nbr[row * MAXDEG + t];
    if (tid < 8) ss[tid] = src2[row * H_ + tid];
    __syncthreads();
    for (int idx = tid; idx < cnt * 8; idx += 256) {
        int n = idx >> 3, h = idx & 7;
        int j = nb[n];
        float e = ss[h] + dst2[(rb + j) * H_ + h];
        ew[n * 8 + h] = e > 0.f ? e : LRELU_ALPHA * e;
    }
    __syncthreads();
    {
        int lane = tid & 63, wv = tid >> 6;
        int h = wv * 2 + (lane >> 5), sub = lane & 31;
        float m = -1e30f;
        for (int n = sub; n < cnt; n += 32) m = fmaxf(m, ew[n * 8 + h]);
        for (int o = 16; o; o >>= 1) m = fmaxf(m, __shfl_xor(m, o));
        float s = 0.f;
        for (int n = sub; n < cnt; n += 32) {
            float v = __expf(ew[n * 8 + h] - m); ew[n * 8 + h] = v; s += v;
        }
        for (int o = 16; o; o >>= 1) s += __shfl_xor(s, o);
        float inv = s > 0.f ? 0.125f / s : 0.f;
        for (int n = sub; n < cnt; n += 32) ew[n * 8 + h] *= inv;
    }
    __syncthreads();
    // thread: dims (2dp, 2dp+1), heads hg*4..hg*4+3
    int dp = tid & 127, hg = tid >> 7;
    const unsigned short* hbase = Hb + (size_t)rb * 256 + 2 * dp;
    const float* ewh = ew + hg * 4;
    float a0x = 0.f, a0y = 0.f, a0z = 0.f, a0w = 0.f;   // dim0 x heads
    float a1x = 0.f, a1y = 0.f, a1z = 0.f, a1w = 0.f;   // dim1 x heads
    int n = 0;
    for (; n + 3 < cnt; n += 4) {
        int j0 = nb[n], j1 = nb[n + 1], j2 = nb[n + 2], j3 = nb[n + 3];
        unsigned int p0 = *(const unsigned int*)(hbase + (size_t)j0 * 256);
        unsigned int p1 = *(const unsigned int*)(hbase + (size_t)j1 * 256);
        unsigned int p2 = *(const unsigned int*)(hbase + (size_t)j2 * 256);
        unsigned int p3 = *(const unsigned int*)(hbase + (size_t)j3 * 256);
        float4 w0 = *(const float4*)(ewh + n * 8);
        float4 w1 = *(const float4*)(ewh + (n + 1) * 8);
        float4 w2 = *(const float4*)(ewh + (n + 2) * 8);
        float4 w3 = *(const float4*)(ewh + (n + 3) * 8);
        float v0a = bf2f((unsigned short)p0), v0b = bf2f((unsigned short)(p0 >> 16));
        float v1a = bf2f((unsigned short)p1), v1b = bf2f((unsigned short)(p1 >> 16));
        float v2a = bf2f((unsigned short)p2), v2b = bf2f((unsigned short)(p2 >> 16));
        float v3a = bf2f((unsigned short)p3), v3b = bf2f((unsigned short)(p3 >> 16));
        a0x += w0.x * v0a + w1.x * v1a + w2.x * v2a + w3.x * v3a;
        a0y += w0.y * v0a + w1.y * v1a + w2.y * v2a + w3.y * v3a;
        a0z += w0.z * v0a + w1.z * v1a + w2.z * v2a + w3.z * v3a;
        a0w += w0.w * v0a + w1.w * v1a + w2.w * v2a + w3.w * v3a;
        a1x += w0.x * v0b + w1.x * v1b + w2.x * v2b + w3.x * v3b;
        a1y += w0.y * v0b + w1.y * v1b + w2.y * v2b + w3.y * v3b;
        a1z += w0.z * v0b + w1.z * v1b + w2.z * v2b + w3.z * v3b;
        a1w += w0.w * v0b + w1.w * v1b + w2.w * v2b + w3.w * v3b;
    }
    for (; n < cnt; ++n) {
        int j = nb[n];
        unsigned int p = *(const unsigned int*)(hbase + (size_t)j * 256);
        float4 w = *(const float4*)(ewh + n * 8);
        float va = bf2f((unsigned short)p), vb = bf2f((unsigned short)(p >> 16));
        a0x += w.x * va; a0y += w.y * va; a0z += w.z * va; a0w += w.w * va;
        a1x += w.x * vb; a1y += w.y * vb; a1z += w.z * vb; a1w += w.w * vb;
    }
    unsigned short* yb = Ycat + (size_t)row * 2048 + (hg * 4) * 256 + 2 * dp;
    ushort2 u;
    u.x = f2bf(a0x); u.y = f2bf(a1x); *(ushort2*)(yb)         = u;
    u.x = f2bf(a0y); u.y = f2bf(a1y); *(ushort2*)(yb + 256)   = u;
    u.x = f2bf(a0z); u.y = f2bf(a1z); *(ushort2*)(yb + 512)   = u;
    u.x = f2bf(a0w); u.y = f2bf(a1w); *(ushort2*)(yb + 768)   = u;
}

// ------- 8-way split reduce + residual + LayerNorm, fp32 + bf16 out -------
__global__ __launch_bounds__(256) void k_ln_red(const float* __restrict__ P, int nsplit,
        const float* __restrict__ Hres, const float* __restrict__ g,
        const float* __restrict__ bta, float* __restrict__ HLN,
        unsigned short* __restrict__ HLNb) {
    int row = blockIdx.x * 4 + (threadIdx.x >> 6);
    int lane = threadIdx.x & 63;
    float4 v = ((const float4*)(Hres + (size_t)row * 256))[lane];
    for (int sp = 0; sp < nsplit; ++sp) {
        float4 p = ((const float4*)(P + (size_t)sp * 1048576 + (size_t)row * 256))[lane];
        v.x += p.x; v.y += p.y; v.z += p.z; v.w += p.w;
    }
    float s = v.x + v.y + v.z + v.w;
    float q = v.x * v.x + v.y * v.y + v.z * v.z + v.w * v.w;
    for (int o = 32; o; o >>= 1) { s += __shfl_xor(s, o); q += __shfl_xor(q, o); }
    float mu = s * (1.f / 256.f);
    float var = q * (1.f / 256.f) - mu * mu;
    if (var < 0.f) var = 0.f;
    float rs = rsqrtf(var + 1e-5f);
    float4 gg = ((const float4*)g)[lane];
    float4 bb = ((const float4*)bta)[lane];
    float4 o;
    o.x = (v.x - mu) * rs * gg.x + bb.x;
    o.y = (v.y - mu) * rs * gg.y + bb.y;
    o.z = (v.z - mu) * rs * gg.z + bb.z;
    o.w = (v.w - mu) * rs * gg.w + bb.w;
    ((float4*)(HLN + (size_t)row * 256))[lane] = o;
    ushort4 ob; ob.x = f2bf(o.x); ob.y = f2bf(o.y); ob.z = f2bf(o.z); ob.w = f2bf(o.w);
    ((ushort4*)(HLNb + (size_t)row * 256))[lane] = ob;
}

// ---------------- split reduce + bias + gelu -> bf16 ----------------
__global__ void k_red_gelu(const float* __restrict__ P, const float* __restrict__ b1,
                           unsigned short* __restrict__ out, int n, int nsplit, int cmask4) {
    int i = blockIdx.x * blockDim.x + threadIdx.x;
    if (i >= (n >> 2)) return;
    float4 s = ((const float4*)P)[i];
    for (int sp = 1; sp < nsplit; ++sp) {
        float4 v = ((const float4*)(P + (size_t)sp * n))[i];
        s.x += v.x; s.y += v.y; s.z += v.z; s.w += v.w;
    }
    float4 bb = ((const float4*)b1)[i & cmask4];
    float xs[4] = {s.x + bb.x, s.y + bb.y, s.z + bb.z, s.w + bb.w};
    ushort4 u;
    unsigned short* up = (unsigned short*)&u;
#pragma unroll
    for (int q = 0; q < 4; ++q) {
        float x = xs[q];
        float t = tanhf(0.7978845608028654f * (x + 0.044715f * x * x * x));
        up[q] = f2bf(0.5f * x * (1.f + t));
    }
    ((ushort4*)out)[i] = u;
}

// ---------------- split reduce + residual + bias -> fp32 (final) ----------------
__global__ void k_red_final(const float* __restrict__ P, const float* __restrict__ HLN,
                            const float* __restrict__ b2, float* __restrict__ out,
                            int n, int nsplit) {
    int i = blockIdx.x * blockDim.x + threadIdx.x;
    if (i >= (n >> 2)) return;
    float4 s = ((const float4*)HLN)[i];
    float4 bb = ((const float4*)b2)[i & 63];
    s.x += bb.x; s.y += bb.y; s.z += bb.z; s.w += bb.w;
    for (int sp = 0; sp < nsplit; ++sp) {
        float4 v = ((const float4*)(P + (size_t)sp * n))[i];
        s.x += v.x; s.y += v.y; s.z += v.z; s.w += v.w;
    }
    ((float4*)out)[i] = s;
}

extern "C" void kernel_launch(void* const* d_in, const int* in_sizes, int n_in,
                              void* d_out, int out_size, void* d_ws, size_t ws_size,
                              hipStream_t stream) {
    const float* adj   = (const float*)d_in[0];
    const float* x     = (const float*)d_in[1];
    const float* W0    = (const float*)d_in[2];
    const float* as0   = (const float*)d_in[3];
    const float* ad0   = (const float*)d_in[4];
    const float* W1    = (const float*)d_in[5];
    const float* as1   = (const float*)d_in[6];
    const float* ad1   = (const float*)d_in[7];
    const float* W2    = (const float*)d_in[8];
    const float* as2   = (const float*)d_in[9];
    const float* ad2   = (const float*)d_in[10];
    const float* ln_g  = (const float*)d_in[11];
    const float* ln_b  = (const float*)d_in[12];
    const float* ff_w1 = (const float*)d_in[13];
    const float* ff_b1 = (const float*)d_in[14];
    const float* ff_w2 = (const float*)d_in[15];
    const float* ff_b2 = (const float*)d_in[16];

    float* ws = (float*)d_ws;
    float* H    = ws;                          // [4096,256] f32
    float* HLN  = ws + 1048576;                // [4096,256] f32
    unsigned short* Ycat = (unsigned short*)(ws + 2097152);   // [4096,2048] bf16
    unsigned short* HPb  = (unsigned short*)(ws + 6291456);   // [4096,256] bf16
    unsigned short* xb   = (unsigned short*)(ws + 6815744);
    unsigned short* Hb   = (unsigned short*)(ws + 7340032);
    unsigned short* HLNb = (unsigned short*)(ws + 7864320);
    unsigned short* MIDb = (unsigned short*)(ws + 8388608);   // [4096,512] bf16
    unsigned short* W0t  = (unsigned short*)(ws + 9437184);   // [256,256]
    unsigned short* W1t  = (unsigned short*)(ws + 9469952);
    unsigned short* W2t  = (unsigned short*)(ws + 9502720);   // [256,2048]
    unsigned short* F1t  = (unsigned short*)(ws + 9764864);   // [512,256]
    unsigned short* F2t  = (unsigned short*)(ws + 9830400);   // [256,512]
    float* WS2  = ws + 9895936;                // [8,256]
    float* WD2  = ws + 9897984;                // [8,256]
    float* SRC  = ws + 9900032;                // [4096,8]
    float* DST  = ws + 9932800;
    float* SRC2 = ws + 9965568;                // [4096,8] layer-2 scores
    float* DST2 = ws + 9998336;
    int*   NBR  = (int*)(ws + 10031104);       // [4096,128]
    int*   CNT  = (int*)(ws + 10555392);
    float* PP   = ws + 12582912;               // split-K partials, up to [8][4096][256] f32

    // one prep kernel: CSR + casts + transposes + wvec2
    k_prep<<<6024, 256, 0, stream>>>(x, xb, W0, W0t, W1, W1t, W2, W2t,
                                     ff_w1, F1t, ff_w2, F2t, as2, ad2, WS2, WD2,
                                     adj, NBR, CNT);

    // ---- GAT layer 0 ----
    k_gemm_wide<<<dim3(1, 64, 4), 256, 0, stream>>>(xb, W0t, PP, 4096, 256, 256, 64);
    k_red_scores<<<4096, 256, 0, stream>>>(PP, 4, as0, ad0, HPb, SRC, DST);
    k_attn_small_f<<<4096, 256, 0, stream>>>(HPb, SRC, DST, NBR, CNT, x, H, Hb,
                                             nullptr, nullptr, nullptr, nullptr);

    // ---- GAT layer 1 (layer-2 scores fused into epilogue) ----
    k_gemm_wide<<<dim3(1, 64, 4), 256, 0, stream>>>(Hb, W1t, PP, 4096, 256, 256, 64);
    k_red_scores<<<4096, 256, 0, stream>>>(PP, 4, as1, ad1, HPb, SRC, DST);
    k_attn_small_f<<<4096, 256, 0, stream>>>(HPb, SRC, DST, NBR, CNT, H, H, Hb,
                                             WS2, WD2, SRC2, DST2);

    // ---- GAT layer 2: aggregate H, GEMM with W2 (split 8), LN fused ----
    k_attn_Y<<<4096, 256, 0, stream>>>(Hb, SRC2, DST2, NBR, CNT, Ycat);
    k_gemm_wide<<<dim3(1, 64, 8), 256, 0, stream>>>(Ycat, W2t, PP, 4096, 256, 2048, 256);
    k_ln_red<<<1024, 256, 0, stream>>>(PP, 8, H, ln_g, ln_b, HLN, HLNb);

    // ---- FFN ----
    k_gemm_wide<<<dim3(2, 64, 2), 256, 0, stream>>>(HLNb, F1t, PP, 4096, 512, 256, 128);
    k_red_gelu<<<2048, 256, 0, stream>>>(PP, ff_b1, MIDb, 2097152, 2, 127);
    k_gemm_wide<<<dim3(1, 64, 4), 256, 0, stream>>>(MIDb, F2t, PP, 4096, 256, 512, 128);
    k_red_final<<<1024, 256, 0, stream>>>(PP, HLN, ff_b2, (float*)d_out, 1048576, 4);
}